// Round 10
// baseline (242.410 us; speedup 1.0000x reference)
//
#include <hip/hip_runtime.h>

#define XS_STRIDE 72
#define MAXBUK 256
#define BF_CHUNK 4096

typedef unsigned short ushort_t;
typedef unsigned int uint_t;
typedef __attribute__((ext_vector_type(8))) short short8_t;
typedef __attribute__((ext_vector_type(4))) float f32x4;

__device__ __forceinline__ ushort_t f2bf(float x) {
    uint_t u = __float_as_uint(x);
    uint_t r = (u + 0x7FFFu + ((u >> 16) & 1u)) >> 16;
    return (ushort_t)r;
}
__device__ __forceinline__ float bf2f(ushort_t h) {
    return __uint_as_float((uint_t)h << 16);
}

__global__ void zero_int_kernel(int* p, int n) {
    int i = blockIdx.x * blockDim.x + threadIdx.x;
    if (i < n) p[i] = 0;
}

__global__ void bhist2_kernel(const int* __restrict__ dsta, const int* __restrict__ dstb,
                              int* __restrict__ bcnt2,
                              int Ea, int Et, int shift, int nbuk) {
    __shared__ int h[MAXBUK];
    for (int i = threadIdx.x; i < 2 * nbuk; i += blockDim.x) h[i] = 0;
    __syncthreads();
    int stride = gridDim.x * blockDim.x;
    for (int e = blockIdx.x * blockDim.x + threadIdx.x; e < Et; e += stride) {
        int rel = (e >= Ea);
        int d = rel ? dstb[e - Ea] : dsta[e];
        atomicAdd(&h[(rel ? nbuk : 0) + (d >> shift)], 1);
    }
    __syncthreads();
    for (int i = threadIdx.x; i < 2 * nbuk; i += blockDim.x)
        if (h[i]) atomicAdd(&bcnt2[i], h[i]);
}

__global__ void bscan_kernel(const int* __restrict__ bcnt, int* __restrict__ bbase,
                             int* __restrict__ bcursor, int nbuk2,
                             int* __restrict__ rowptr2, int n2, int Et) {
    __shared__ int s[256];
    int t = threadIdx.x;
    int v = (t < nbuk2) ? bcnt[t] : 0;
    s[t] = v;
    __syncthreads();
    #pragma unroll
    for (int d = 1; d < 256; d <<= 1) {
        int u = (t >= d) ? s[t - d] : 0;
        __syncthreads();
        s[t] += u;
        __syncthreads();
    }
    if (t < nbuk2) { int e = s[t] - v; bbase[t] = e; bcursor[t] = e; }
    if (t == 0) rowptr2[n2] = Et;
}

// Bin packed (src<<shift | dst_local) by combined bucket id.
__global__ void bfill2_kernel(const int* __restrict__ eia, const int* __restrict__ eib,
                              int* __restrict__ bcursor, uint_t* __restrict__ pairs,
                              int Ea, int Eb, int Et, int shift, int nbuk, int n) {
    __shared__ int cnt[MAXBUK];
    __shared__ int base[MAXBUK];
    __shared__ int off[MAXBUK];
    const int t = threadIdx.x;
    const long long e0 = (long long)blockIdx.x * BF_CHUNK;
    const int nedge = (int)min((long long)BF_CHUNK, (long long)Et - e0);
    const int nbuk2 = 2 * nbuk;
    const uint_t mask = (1u << shift) - 1u;
    for (int i = t; i < nbuk2; i += 256) cnt[i] = 0;
    __syncthreads();
    for (int i = t; i < nedge; i += 256) {
        long long e = e0 + i;
        int rel = (e >= Ea);
        int d = rel ? eib[Eb + (e - Ea)] : eia[Ea + e];
        atomicAdd(&cnt[(rel ? nbuk : 0) + (d >> shift)], 1);
    }
    __syncthreads();
    for (int i = t; i < nbuk2; i += 256) {
        off[i] = 0;
        base[i] = cnt[i] ? atomicAdd(&bcursor[i], cnt[i]) : 0;
    }
    __syncthreads();
    for (int i = t; i < nedge; i += 256) {
        long long e = e0 + i;
        int rel = (e >= Ea);
        int s, d;
        if (rel) { s = eib[e - Ea]; d = eib[Eb + (e - Ea)]; }
        else     { s = eia[e];      d = eia[Ea + e]; }
        int b = (rel ? nbuk : 0) + (d >> shift);
        int p = base[b] + atomicAdd(&off[b], 1);
        pairs[p] = ((uint_t)s << shift) | ((uint_t)d & mask);
    }
}

// Per-bucket CSR build from packed pairs. NPB = 1<<shift.
template<int NPB>
__global__ void bucket_csr_kernel(const uint_t* __restrict__ pairs,
                                  const int* __restrict__ bbase2, const int* __restrict__ bcnt2,
                                  int* __restrict__ rowptr2, float* __restrict__ dinv2,
                                  int* __restrict__ col2,
                                  int nbuk, int shift, int n) {
    constexpr int BLK = 1024;
    constexpr int K = NPB / BLK;
    constexpr uint_t MASK = NPB - 1;
    __shared__ int cnt[NPB];
    __shared__ int ssum[BLK];
    const int b = blockIdx.x;
    const int t = threadIdx.x;
    const int rel = (b >= nbuk);
    const int blocal = rel ? b - nbuk : b;
    const int nodelo = blocal << shift;
    const int node0 = (rel ? n : 0) + nodelo;
    const int NN = min(NPB, n - nodelo);
    const int p0 = bbase2[b];
    const int p1 = p0 + bcnt2[b];

    #pragma unroll
    for (int k = 0; k < K; ++k) cnt[t + k * BLK] = 0;
    __syncthreads();
    for (int idx = p0 + t; idx < p1; idx += BLK)
        atomicAdd(&cnt[pairs[idx] & MASK], 1);
    __syncthreads();

    int a[K]; int s = 0;
    #pragma unroll
    for (int k = 0; k < K; ++k) { a[k] = cnt[t * K + k]; s += a[k]; }
    ssum[t] = s;
    __syncthreads();
    #pragma unroll
    for (int d = 1; d < BLK; d <<= 1) {
        int u = (t >= d) ? ssum[t - d] : 0;
        __syncthreads();
        ssum[t] += u;
        __syncthreads();
    }
    int run = p0 + ssum[t] - s;
    __syncthreads();
    #pragma unroll
    for (int k = 0; k < K; ++k) {
        int j = t * K + k;
        cnt[j] = run;
        if (j < NN) {
            rowptr2[node0 + j] = run;
            dinv2[node0 + j] = rsqrtf((float)(a[k] + 1));
        }
        run += a[k];
    }
    __syncthreads();
    for (int idx = p0 + t; idx < p1; idx += BLK) {
        uint_t p = pairs[idx];
        int pos = atomicAdd(&cnt[p & MASK], 1);
        col2[pos] = (int)(p >> shift);
    }
}

// ---- MFMA dual-weight GEMM (layer 1): ya|yb = (Xbf16 @ [Wa|Wb]) * dinv, bf16 out ----
__global__ void gemm2_mfma_bf16_kernel(const float* __restrict__ X,
                                       const float* __restrict__ Wa, const float* __restrict__ Wb,
                                       const float* __restrict__ dinva, const float* __restrict__ dinvb,
                                       ushort_t* __restrict__ ya, ushort_t* __restrict__ yb, int n) {
    __shared__ ushort_t Xs[64 * XS_STRIDE];
    __shared__ ushort_t Wt[128 * XS_STRIDE];
    const int tid = threadIdx.x;
    const int rowbase = blockIdx.x * 64;

    {
        int row = tid >> 2, cg = tid & 3;
        int grow = rowbase + row;
        float4 v[4];
        if (grow < n) {
            const float4* xr = reinterpret_cast<const float4*>(X + (size_t)grow * 64 + cg * 16);
            v[0] = xr[0]; v[1] = xr[1]; v[2] = xr[2]; v[3] = xr[3];
        } else {
            v[0] = v[1] = v[2] = v[3] = make_float4(0.f, 0.f, 0.f, 0.f);
        }
        ushort_t* dst = &Xs[row * XS_STRIDE + cg * 16];
        #pragma unroll
        for (int q = 0; q < 4; ++q) {
            dst[q * 4 + 0] = f2bf(v[q].x); dst[q * 4 + 1] = f2bf(v[q].y);
            dst[q * 4 + 2] = f2bf(v[q].z); dst[q * 4 + 3] = f2bf(v[q].w);
        }
    }
    for (int idx = tid; idx < 4096; idx += 256) {
        int k = idx >> 6, c = idx & 63;
        Wt[c * XS_STRIDE + k] = f2bf(Wa[idx]);
        Wt[(64 + c) * XS_STRIDE + k] = f2bf(Wb[idx]);
    }
    __syncthreads();

    const int wid = tid >> 6, lane = tid & 63;
    const int lrow = lane & 15;
    const int lk = (lane >> 4) * 8;

    short8_t a0 = *reinterpret_cast<const short8_t*>(&Xs[(wid * 16 + lrow) * XS_STRIDE + lk]);
    short8_t a1 = *reinterpret_cast<const short8_t*>(&Xs[(wid * 16 + lrow) * XS_STRIDE + 32 + lk]);

    f32x4 acc[8];
    #pragma unroll
    for (int ct = 0; ct < 8; ++ct) {
        short8_t b0 = *reinterpret_cast<const short8_t*>(&Wt[(ct * 16 + lrow) * XS_STRIDE + lk]);
        short8_t b1 = *reinterpret_cast<const short8_t*>(&Wt[(ct * 16 + lrow) * XS_STRIDE + 32 + lk]);
        f32x4 c = {0.f, 0.f, 0.f, 0.f};
        c = __builtin_amdgcn_mfma_f32_16x16x32_bf16(a0, b0, c, 0, 0, 0);
        c = __builtin_amdgcn_mfma_f32_16x16x32_bf16(a1, b1, c, 0, 0, 0);
        acc[ct] = c;
    }

    const int rq = (lane >> 4) * 4;
    #pragma unroll
    for (int r = 0; r < 4; ++r) {
        int grow = rowbase + wid * 16 + rq + r;
        if (grow < n) {
            float sa = dinva[grow], sb = dinvb[grow];
            #pragma unroll
            for (int ct = 0; ct < 8; ++ct) {
                int col = ct * 16 + lrow;
                float v = acc[ct][r];
                if (col < 64) ya[(size_t)grow * 64 + col] = f2bf(v * sa);
                else          yb[(size_t)grow * 64 + (col - 64)] = f2bf(v * sb);
            }
        }
    }
}

// ---- MFMA layer-2 GEMM: za|zb = (Hbf16 @ [W2a|W2b]) * dinv, bf16 out ----
__global__ void gemm2_mfma_h_kernel(const ushort_t* __restrict__ H,
                                    const float* __restrict__ W2a, const float* __restrict__ W2b,
                                    const float* __restrict__ dinva, const float* __restrict__ dinvb,
                                    ushort_t* __restrict__ za, ushort_t* __restrict__ zb, int n) {
    __shared__ ushort_t Hs[64 * XS_STRIDE];
    __shared__ ushort_t Wt[32 * XS_STRIDE];
    const int tid = threadIdx.x;
    const int rowbase = blockIdx.x * 64;

    {
        int row = tid >> 2, cg = tid & 3;
        int grow = rowbase + row;
        uint4 v0 = {0, 0, 0, 0}, v1 = {0, 0, 0, 0};
        if (grow < n) {
            const uint4* hr = reinterpret_cast<const uint4*>(H + (size_t)grow * 64 + cg * 16);
            v0 = hr[0]; v1 = hr[1];
        }
        uint4* dst = reinterpret_cast<uint4*>(&Hs[row * XS_STRIDE + cg * 16]);
        dst[0] = v0; dst[1] = v1;
    }
    for (int idx = tid; idx < 2048; idx += 256) {
        int c = idx & 31, k = idx >> 5;
        float v = (c < 16) ? W2a[k * 16 + c] : W2b[k * 16 + (c - 16)];
        Wt[c * XS_STRIDE + k] = f2bf(v);
    }
    __syncthreads();

    const int wid = tid >> 6, lane = tid & 63;
    const int lrow = lane & 15;
    const int lk = (lane >> 4) * 8;
    const int rq = (lane >> 4) * 4;

    short8_t a0 = *reinterpret_cast<const short8_t*>(&Hs[(wid * 16 + lrow) * XS_STRIDE + lk]);
    short8_t a1 = *reinterpret_cast<const short8_t*>(&Hs[(wid * 16 + lrow) * XS_STRIDE + 32 + lk]);

    f32x4 c0 = {0.f, 0.f, 0.f, 0.f}, c1 = {0.f, 0.f, 0.f, 0.f};
    {
        short8_t b0 = *reinterpret_cast<const short8_t*>(&Wt[lrow * XS_STRIDE + lk]);
        short8_t b1 = *reinterpret_cast<const short8_t*>(&Wt[lrow * XS_STRIDE + 32 + lk]);
        c0 = __builtin_amdgcn_mfma_f32_16x16x32_bf16(a0, b0, c0, 0, 0, 0);
        c0 = __builtin_amdgcn_mfma_f32_16x16x32_bf16(a1, b1, c0, 0, 0, 0);
    }
    {
        short8_t b0 = *reinterpret_cast<const short8_t*>(&Wt[(16 + lrow) * XS_STRIDE + lk]);
        short8_t b1 = *reinterpret_cast<const short8_t*>(&Wt[(16 + lrow) * XS_STRIDE + 32 + lk]);
        c1 = __builtin_amdgcn_mfma_f32_16x16x32_bf16(a0, b0, c1, 0, 0, 0);
        c1 = __builtin_amdgcn_mfma_f32_16x16x32_bf16(a1, b1, c1, 0, 0, 0);
    }
    #pragma unroll
    for (int r = 0; r < 4; ++r) {
        int node = rowbase + wid * 16 + rq + r;
        if (node < n) {
            za[(size_t)node * 16 + lrow] = f2bf(c0[r] * dinva[node]);
            zb[(size_t)node * 16 + lrow] = f2bf(c1[r] * dinvb[node]);
        }
    }
}

// ---- fused dual-relation aggregation, layer 1 (bf16, F=64), h out bf16 ----
__global__ void agg64_dual_kernel(const ushort_t* __restrict__ ya, const ushort_t* __restrict__ yb,
                                  const int* __restrict__ rp2, const int* __restrict__ col2,
                                  const float* __restrict__ dinv2,
                                  const float* __restrict__ ba, const float* __restrict__ bb,
                                  ushort_t* __restrict__ h, int n) {
    const int lane = threadIdx.x & 63;
    const int gw   = (blockIdx.x * blockDim.x + threadIdx.x) >> 6;
    const int nw   = (gridDim.x * blockDim.x) >> 6;
    const float bias = ba[lane] + bb[lane];
    for (int i = gw; i < n; i += nw) {
        const int e0a = rp2[i],     e1a = rp2[i + 1];
        const int e0b = rp2[n + i], e1b = rp2[n + i + 1];
        float acca = bf2f(ya[(size_t)i * 64 + lane]);
        float accb = bf2f(yb[(size_t)i * 64 + lane]);
        const int ma = min(64, e1a - e0a);
        const int mb = min(64, e1b - e0b);
        int cva = (lane < ma) ? __builtin_nontemporal_load(&col2[e0a + lane]) : 0;
        int cvb = (lane < mb) ? __builtin_nontemporal_load(&col2[e0b + lane]) : 0;
        const int mn = min(ma, mb);
        int j = 0;
        for (; j + 4 <= mn; j += 4) {
            int a0 = __shfl(cva, j),     b0 = __shfl(cvb, j);
            int a1 = __shfl(cva, j + 1), b1 = __shfl(cvb, j + 1);
            int a2 = __shfl(cva, j + 2), b2 = __shfl(cvb, j + 2);
            int a3 = __shfl(cva, j + 3), b3 = __shfl(cvb, j + 3);
            float ga0 = bf2f(ya[(size_t)a0 * 64 + lane]);
            float gb0 = bf2f(yb[(size_t)b0 * 64 + lane]);
            float ga1 = bf2f(ya[(size_t)a1 * 64 + lane]);
            float gb1 = bf2f(yb[(size_t)b1 * 64 + lane]);
            float ga2 = bf2f(ya[(size_t)a2 * 64 + lane]);
            float gb2 = bf2f(yb[(size_t)b2 * 64 + lane]);
            float ga3 = bf2f(ya[(size_t)a3 * 64 + lane]);
            float gb3 = bf2f(yb[(size_t)b3 * 64 + lane]);
            acca += (ga0 + ga1) + (ga2 + ga3);
            accb += (gb0 + gb1) + (gb2 + gb3);
        }
        for (; j < mn; ++j) {
            float ga = bf2f(ya[(size_t)__shfl(cva, j) * 64 + lane]);
            float gb = bf2f(yb[(size_t)__shfl(cvb, j) * 64 + lane]);
            acca += ga; accb += gb;
        }
        for (int ja = j; ja < ma; ++ja)
            acca += bf2f(ya[(size_t)__shfl(cva, ja) * 64 + lane]);
        for (int jb = j; jb < mb; ++jb)
            accb += bf2f(yb[(size_t)__shfl(cvb, jb) * 64 + lane]);
        for (int base = e0a + 64; base < e1a; base += 64) {
            const int m = min(64, e1a - base);
            int c = (lane < m) ? __builtin_nontemporal_load(&col2[base + lane]) : 0;
            for (int jj = 0; jj < m; ++jj)
                acca += bf2f(ya[(size_t)__shfl(c, jj) * 64 + lane]);
        }
        for (int base = e0b + 64; base < e1b; base += 64) {
            const int m = min(64, e1b - base);
            int c = (lane < m) ? __builtin_nontemporal_load(&col2[base + lane]) : 0;
            for (int jj = 0; jj < m; ++jj)
                accb += bf2f(yb[(size_t)__shfl(c, jj) * 64 + lane]);
        }
        float v = 0.5f * (acca * dinv2[i] + accb * dinv2[n + i] + bias);
        __builtin_nontemporal_store(f2bf(fmaxf(v, 0.0f)), &h[(size_t)i * 64 + lane]);
    }
}

// ---- fused dual-relation aggregation, layer 2 (bf16, F=16) ----
__global__ void agg16_dual_kernel(const ushort_t* __restrict__ za, const ushort_t* __restrict__ zb,
                                  const int* __restrict__ rp2, const int* __restrict__ col2,
                                  const float* __restrict__ dinv2,
                                  const float* __restrict__ ba, const float* __restrict__ bb,
                                  float* __restrict__ outp, int n) {
    const int lane = threadIdx.x & 63;
    const int f    = lane & 15;
    const int sub  = lane >> 4;
    const int gw   = (blockIdx.x * blockDim.x + threadIdx.x) >> 6;
    const int nw   = (gridDim.x * blockDim.x) >> 6;
    const float bias = ba[f] + bb[f];
    for (int i = gw; i < n; i += nw) {
        const int e1a = rp2[i + 1],     e1b = rp2[n + i + 1];
        int ea = rp2[i] + sub,          eb = rp2[n + i] + sub;
        float acca = (sub == 0) ? bf2f(za[(size_t)i * 16 + f]) : 0.0f;
        float accb = (sub == 0) ? bf2f(zb[(size_t)i * 16 + f]) : 0.0f;
        for (; ea + 4 < e1a && eb + 4 < e1b; ea += 8, eb += 8) {
            int c0 = __builtin_nontemporal_load(&col2[ea]);
            int c1 = __builtin_nontemporal_load(&col2[ea + 4]);
            int d0 = __builtin_nontemporal_load(&col2[eb]);
            int d1 = __builtin_nontemporal_load(&col2[eb + 4]);
            float g0 = bf2f(za[(size_t)c0 * 16 + f]);
            float g1 = bf2f(za[(size_t)c1 * 16 + f]);
            float g2 = bf2f(zb[(size_t)d0 * 16 + f]);
            float g3 = bf2f(zb[(size_t)d1 * 16 + f]);
            acca += g0 + g1;
            accb += g2 + g3;
        }
        for (; ea < e1a; ea += 4) acca += bf2f(za[(size_t)__builtin_nontemporal_load(&col2[ea]) * 16 + f]);
        for (; eb < e1b; eb += 4) accb += bf2f(zb[(size_t)__builtin_nontemporal_load(&col2[eb]) * 16 + f]);
        float v = acca * dinv2[i] + accb * dinv2[n + i];
        v += __shfl_xor(v, 16);
        v += __shfl_xor(v, 32);
        if (sub == 0) __builtin_nontemporal_store(0.5f * (v + bias), &outp[(size_t)i * 16 + f]);
    }
}

extern "C" void kernel_launch(void* const* d_in, const int* in_sizes, int n_in,
                              void* d_out, int out_size, void* d_ws, size_t ws_size,
                              hipStream_t stream) {
    const float* x   = (const float*)d_in[0];
    const int*   eia = (const int*)d_in[1];
    const int*   eib = (const int*)d_in[2];
    const float* W1a = (const float*)d_in[3];
    const float* b1a = (const float*)d_in[4];
    const float* W1b = (const float*)d_in[5];
    const float* b1b = (const float*)d_in[6];
    const float* W2a = (const float*)d_in[7];
    const float* b2a = (const float*)d_in[8];
    const float* W2b = (const float*)d_in[9];
    const float* b2b = (const float*)d_in[10];
    float* out = (float*)d_out;

    const int n  = in_sizes[0] / 64;
    const int Ea = in_sizes[1] / 2;
    const int Eb = in_sizes[2] / 2;
    const int Et = Ea + Eb;
    const int n2 = 2 * n;

    int shift = 10;
    while ((((long long)n + (1LL << shift) - 1) >> shift) > 128) ++shift;
    const int nbuk = (int)(((long long)n + (1LL << shift) - 1) >> shift);
    const int nbuk2 = 2 * nbuk;

    char* wsp = (char*)d_ws;
    size_t off = 0;
    auto carve = [&](size_t elems) { void* p = wsp + off; off += ((elems + 3) & ~(size_t)3) * 4; return p; };
    float* dinv2    = (float*)carve(n2);
    int*   rowptr2  = (int*)carve(n2 + 1);
    int*   bcnt2    = (int*)carve(MAXBUK);
    int*   bbase2   = (int*)carve(MAXBUK);
    int*   bcursor2 = (int*)carve(MAXBUK);
    int*   col2     = (int*)carve(Et);
    ushort_t* ya    = (ushort_t*)carve((size_t)32 * n);   // 64n bf16
    ushort_t* yb    = (ushort_t*)carve((size_t)32 * n);
    ushort_t* za    = (ushort_t*)carve((size_t)8 * n);    // 16n bf16
    ushort_t* zb    = (ushort_t*)carve((size_t)8 * n);
    // big union: pairs (Et u32 words) dead after bucket_csr; then H (64n bf16 = 32n words)
    size_t big_words = (size_t)Et > (size_t)32 * n ? (size_t)Et : (size_t)32 * n;
    void*  big      = carve(big_words);
    uint_t* pairs   = (uint_t*)big;
    ushort_t* H     = (ushort_t*)big;

    const int T = 256;
    auto cdiv = [](long long a, long long b) { return (unsigned)((a + b - 1) / b); };

    // ---- combined CSR build ----
    zero_int_kernel<<<1, 256, 0, stream>>>(bcnt2, MAXBUK);
    bhist2_kernel<<<cdiv(Et, (long long)T * 16), T, 0, stream>>>(eia + Ea, eib + Eb, bcnt2,
                                                                 Ea, Et, shift, nbuk);
    bscan_kernel<<<1, 256, 0, stream>>>(bcnt2, bbase2, bcursor2, nbuk2, rowptr2, n2, Et);
    bfill2_kernel<<<cdiv(Et, BF_CHUNK), T, 0, stream>>>(eia, eib, bcursor2, pairs,
                                                        Ea, Eb, Et, shift, nbuk, n);
    if (shift == 10)
        bucket_csr_kernel<1024><<<nbuk2, 1024, 0, stream>>>(pairs, bbase2, bcnt2, rowptr2, dinv2,
                                                            col2, nbuk, shift, n);
    else if (shift == 11)
        bucket_csr_kernel<2048><<<nbuk2, 1024, 0, stream>>>(pairs, bbase2, bcnt2, rowptr2, dinv2,
                                                            col2, nbuk, shift, n);
    else
        bucket_csr_kernel<4096><<<nbuk2, 1024, 0, stream>>>(pairs, bbase2, bcnt2, rowptr2, dinv2,
                                                            col2, nbuk, shift, n);

    const unsigned AGG_GRID = 2048;

    // ---- layer 1 ----
    gemm2_mfma_bf16_kernel<<<cdiv(n, 64), T, 0, stream>>>(x, W1a, W1b, dinv2, dinv2 + n, ya, yb, n);
    agg64_dual_kernel<<<AGG_GRID, T, 0, stream>>>(ya, yb, rowptr2, col2, dinv2, b1a, b1b, H, n);

    // ---- layer 2 ----
    gemm2_mfma_h_kernel<<<cdiv(n, 64), T, 0, stream>>>(H, W2a, W2b, dinv2, dinv2 + n, za, zb, n);
    agg16_dual_kernel<<<AGG_GRID, T, 0, stream>>>(za, zb, rowptr2, col2, dinv2, b2a, b2b, out, n);
}

// Round 11
// 226.959 us; speedup vs baseline: 1.0681x; 1.0681x over previous
//
#include <hip/hip_runtime.h>

#define XS_STRIDE 72
#define MAXBUK 256
#define BF_CHUNK 4096

typedef unsigned short ushort_t;
typedef unsigned int uint_t;
typedef __attribute__((ext_vector_type(8))) short short8_t;
typedef __attribute__((ext_vector_type(4))) float f32x4;

__device__ __forceinline__ ushort_t f2bf(float x) {
    uint_t u = __float_as_uint(x);
    uint_t r = (u + 0x7FFFu + ((u >> 16) & 1u)) >> 16;
    return (ushort_t)r;
}
__device__ __forceinline__ float bf2f(ushort_t h) {
    return __uint_as_float((uint_t)h << 16);
}

__global__ void zero_int_kernel(int* p, int n) {
    int i = blockIdx.x * blockDim.x + threadIdx.x;
    if (i < n) p[i] = 0;
}

__global__ void bhist2_kernel(const int* __restrict__ dsta, const int* __restrict__ dstb,
                              int* __restrict__ bcnt2,
                              int Ea, int Et, int shift, int nbuk) {
    __shared__ int h[MAXBUK];
    for (int i = threadIdx.x; i < 2 * nbuk; i += blockDim.x) h[i] = 0;
    __syncthreads();
    int stride = gridDim.x * blockDim.x;
    for (int e = blockIdx.x * blockDim.x + threadIdx.x; e < Et; e += stride) {
        int rel = (e >= Ea);
        int d = rel ? dstb[e - Ea] : dsta[e];
        atomicAdd(&h[(rel ? nbuk : 0) + (d >> shift)], 1);
    }
    __syncthreads();
    for (int i = threadIdx.x; i < 2 * nbuk; i += blockDim.x)
        if (h[i]) atomicAdd(&bcnt2[i], h[i]);
}

__global__ void bscan_kernel(const int* __restrict__ bcnt, int* __restrict__ bbase,
                             int* __restrict__ bcursor, int nbuk2,
                             int* __restrict__ rowptr2, int n2, int Et) {
    __shared__ int s[256];
    int t = threadIdx.x;
    int v = (t < nbuk2) ? bcnt[t] : 0;
    s[t] = v;
    __syncthreads();
    #pragma unroll
    for (int d = 1; d < 256; d <<= 1) {
        int u = (t >= d) ? s[t - d] : 0;
        __syncthreads();
        s[t] += u;
        __syncthreads();
    }
    if (t < nbuk2) { int e = s[t] - v; bbase[t] = e; bcursor[t] = e; }
    if (t == 0) rowptr2[n2] = Et;
}

// Bin packed (src<<shift | dst_local) by combined bucket id.
__global__ void bfill2_kernel(const int* __restrict__ eia, const int* __restrict__ eib,
                              int* __restrict__ bcursor, uint_t* __restrict__ pairs,
                              int Ea, int Eb, int Et, int shift, int nbuk, int n) {
    __shared__ int cnt[MAXBUK];
    __shared__ int base[MAXBUK];
    __shared__ int off[MAXBUK];
    const int t = threadIdx.x;
    const long long e0 = (long long)blockIdx.x * BF_CHUNK;
    const int nedge = (int)min((long long)BF_CHUNK, (long long)Et - e0);
    const int nbuk2 = 2 * nbuk;
    const uint_t mask = (1u << shift) - 1u;
    for (int i = t; i < nbuk2; i += 256) cnt[i] = 0;
    __syncthreads();
    for (int i = t; i < nedge; i += 256) {
        long long e = e0 + i;
        int rel = (e >= Ea);
        int d = rel ? eib[Eb + (e - Ea)] : eia[Ea + e];
        atomicAdd(&cnt[(rel ? nbuk : 0) + (d >> shift)], 1);
    }
    __syncthreads();
    for (int i = t; i < nbuk2; i += 256) {
        off[i] = 0;
        base[i] = cnt[i] ? atomicAdd(&bcursor[i], cnt[i]) : 0;
    }
    __syncthreads();
    for (int i = t; i < nedge; i += 256) {
        long long e = e0 + i;
        int rel = (e >= Ea);
        int s, d;
        if (rel) { s = eib[e - Ea]; d = eib[Eb + (e - Ea)]; }
        else     { s = eia[e];      d = eia[Ea + e]; }
        int b = (rel ? nbuk : 0) + (d >> shift);
        int p = base[b] + atomicAdd(&off[b], 1);
        pairs[p] = ((uint_t)s << shift) | ((uint_t)d & mask);
    }
}

// Per-bucket CSR build from packed pairs. NPB = 1<<shift.
// Wave-shfl scan (2 barriers) instead of 1024-wide ladder (10 barriers).
template<int NPB>
__global__ void bucket_csr_kernel(const uint_t* __restrict__ pairs,
                                  const int* __restrict__ bbase2, const int* __restrict__ bcnt2,
                                  int* __restrict__ rowptr2, float* __restrict__ dinv2,
                                  int* __restrict__ col2,
                                  int nbuk, int shift, int n) {
    constexpr int BLK = 1024;
    constexpr int K = NPB / BLK;
    constexpr uint_t MASK = NPB - 1;
    __shared__ int cnt[NPB];
    __shared__ int wsum[16];
    const int b = blockIdx.x;
    const int t = threadIdx.x;
    const int lane = t & 63;
    const int w = t >> 6;
    const int rel = (b >= nbuk);
    const int blocal = rel ? b - nbuk : b;
    const int nodelo = blocal << shift;
    const int node0 = (rel ? n : 0) + nodelo;
    const int NN = min(NPB, n - nodelo);
    const int p0 = bbase2[b];
    const int p1 = p0 + bcnt2[b];

    #pragma unroll
    for (int k = 0; k < K; ++k) cnt[t + k * BLK] = 0;
    __syncthreads();
    for (int idx = p0 + t; idx < p1; idx += BLK)
        atomicAdd(&cnt[pairs[idx] & MASK], 1);
    __syncthreads();

    int a[K]; int s = 0;
    #pragma unroll
    for (int k = 0; k < K; ++k) { a[k] = cnt[t * K + k]; s += a[k]; }
    // wave-level inclusive scan of s
    int sc = s;
    #pragma unroll
    for (int d = 1; d < 64; d <<= 1) {
        int u = __shfl_up(sc, d);
        if (lane >= d) sc += u;
    }
    if (lane == 63) wsum[w] = sc;
    __syncthreads();
    if (t < 16) {
        int v = wsum[t];
        int scc = v;
        #pragma unroll
        for (int d = 1; d < 16; d <<= 1) {
            int u = __shfl_up(scc, d);
            if (t >= d) scc += u;
        }
        wsum[t] = scc - v;   // exclusive wave prefix
    }
    __syncthreads();
    int run = p0 + wsum[w] + sc - s;   // exclusive prefix for this thread
    __syncthreads();
    #pragma unroll
    for (int k = 0; k < K; ++k) {
        int j = t * K + k;
        cnt[j] = run;
        if (j < NN) {
            rowptr2[node0 + j] = run;
            dinv2[node0 + j] = rsqrtf((float)(a[k] + 1));
        }
        run += a[k];
    }
    __syncthreads();
    for (int idx = p0 + t; idx < p1; idx += BLK) {
        uint_t p = pairs[idx];
        int pos = atomicAdd(&cnt[p & MASK], 1);
        col2[pos] = (int)(p >> shift);
    }
}

// ---- MFMA dual-weight GEMM (layer 1): ya|yb = (Xbf16 @ [Wa|Wb]) * dinv, bf16 out ----
__global__ void gemm2_mfma_bf16_kernel(const float* __restrict__ X,
                                       const float* __restrict__ Wa, const float* __restrict__ Wb,
                                       const float* __restrict__ dinva, const float* __restrict__ dinvb,
                                       ushort_t* __restrict__ ya, ushort_t* __restrict__ yb, int n) {
    __shared__ ushort_t Xs[64 * XS_STRIDE];
    __shared__ ushort_t Wt[128 * XS_STRIDE];
    const int tid = threadIdx.x;
    const int rowbase = blockIdx.x * 64;

    {
        int row = tid >> 2, cg = tid & 3;
        int grow = rowbase + row;
        float4 v[4];
        if (grow < n) {
            const float4* xr = reinterpret_cast<const float4*>(X + (size_t)grow * 64 + cg * 16);
            v[0] = xr[0]; v[1] = xr[1]; v[2] = xr[2]; v[3] = xr[3];
        } else {
            v[0] = v[1] = v[2] = v[3] = make_float4(0.f, 0.f, 0.f, 0.f);
        }
        ushort_t* dst = &Xs[row * XS_STRIDE + cg * 16];
        #pragma unroll
        for (int q = 0; q < 4; ++q) {
            dst[q * 4 + 0] = f2bf(v[q].x); dst[q * 4 + 1] = f2bf(v[q].y);
            dst[q * 4 + 2] = f2bf(v[q].z); dst[q * 4 + 3] = f2bf(v[q].w);
        }
    }
    for (int idx = tid; idx < 4096; idx += 256) {
        int k = idx >> 6, c = idx & 63;
        Wt[c * XS_STRIDE + k] = f2bf(Wa[idx]);
        Wt[(64 + c) * XS_STRIDE + k] = f2bf(Wb[idx]);
    }
    __syncthreads();

    const int wid = tid >> 6, lane = tid & 63;
    const int lrow = lane & 15;
    const int lk = (lane >> 4) * 8;

    short8_t a0 = *reinterpret_cast<const short8_t*>(&Xs[(wid * 16 + lrow) * XS_STRIDE + lk]);
    short8_t a1 = *reinterpret_cast<const short8_t*>(&Xs[(wid * 16 + lrow) * XS_STRIDE + 32 + lk]);

    f32x4 acc[8];
    #pragma unroll
    for (int ct = 0; ct < 8; ++ct) {
        short8_t b0 = *reinterpret_cast<const short8_t*>(&Wt[(ct * 16 + lrow) * XS_STRIDE + lk]);
        short8_t b1 = *reinterpret_cast<const short8_t*>(&Wt[(ct * 16 + lrow) * XS_STRIDE + 32 + lk]);
        f32x4 c = {0.f, 0.f, 0.f, 0.f};
        c = __builtin_amdgcn_mfma_f32_16x16x32_bf16(a0, b0, c, 0, 0, 0);
        c = __builtin_amdgcn_mfma_f32_16x16x32_bf16(a1, b1, c, 0, 0, 0);
        acc[ct] = c;
    }

    const int rq = (lane >> 4) * 4;
    #pragma unroll
    for (int r = 0; r < 4; ++r) {
        int grow = rowbase + wid * 16 + rq + r;
        if (grow < n) {
            float sa = dinva[grow], sb = dinvb[grow];
            #pragma unroll
            for (int ct = 0; ct < 8; ++ct) {
                int col = ct * 16 + lrow;
                float v = acc[ct][r];
                if (col < 64) ya[(size_t)grow * 64 + col] = f2bf(v * sa);
                else          yb[(size_t)grow * 64 + (col - 64)] = f2bf(v * sb);
            }
        }
    }
}

// ---- MFMA layer-2 GEMM: za|zb = (Hbf16 @ [W2a|W2b]) * dinv, bf16 out ----
__global__ void gemm2_mfma_h_kernel(const ushort_t* __restrict__ H,
                                    const float* __restrict__ W2a, const float* __restrict__ W2b,
                                    const float* __restrict__ dinva, const float* __restrict__ dinvb,
                                    ushort_t* __restrict__ za, ushort_t* __restrict__ zb, int n) {
    __shared__ ushort_t Hs[64 * XS_STRIDE];
    __shared__ ushort_t Wt[32 * XS_STRIDE];
    const int tid = threadIdx.x;
    const int rowbase = blockIdx.x * 64;

    {
        int row = tid >> 2, cg = tid & 3;
        int grow = rowbase + row;
        uint4 v0 = {0, 0, 0, 0}, v1 = {0, 0, 0, 0};
        if (grow < n) {
            const uint4* hr = reinterpret_cast<const uint4*>(H + (size_t)grow * 64 + cg * 16);
            v0 = hr[0]; v1 = hr[1];
        }
        uint4* dst = reinterpret_cast<uint4*>(&Hs[row * XS_STRIDE + cg * 16]);
        dst[0] = v0; dst[1] = v1;
    }
    for (int idx = tid; idx < 2048; idx += 256) {
        int c = idx & 31, k = idx >> 5;
        float v = (c < 16) ? W2a[k * 16 + c] : W2b[k * 16 + (c - 16)];
        Wt[c * XS_STRIDE + k] = f2bf(v);
    }
    __syncthreads();

    const int wid = tid >> 6, lane = tid & 63;
    const int lrow = lane & 15;
    const int lk = (lane >> 4) * 8;
    const int rq = (lane >> 4) * 4;

    short8_t a0 = *reinterpret_cast<const short8_t*>(&Hs[(wid * 16 + lrow) * XS_STRIDE + lk]);
    short8_t a1 = *reinterpret_cast<const short8_t*>(&Hs[(wid * 16 + lrow) * XS_STRIDE + 32 + lk]);

    f32x4 c0 = {0.f, 0.f, 0.f, 0.f}, c1 = {0.f, 0.f, 0.f, 0.f};
    {
        short8_t b0 = *reinterpret_cast<const short8_t*>(&Wt[lrow * XS_STRIDE + lk]);
        short8_t b1 = *reinterpret_cast<const short8_t*>(&Wt[lrow * XS_STRIDE + 32 + lk]);
        c0 = __builtin_amdgcn_mfma_f32_16x16x32_bf16(a0, b0, c0, 0, 0, 0);
        c0 = __builtin_amdgcn_mfma_f32_16x16x32_bf16(a1, b1, c0, 0, 0, 0);
    }
    {
        short8_t b0 = *reinterpret_cast<const short8_t*>(&Wt[(16 + lrow) * XS_STRIDE + lk]);
        short8_t b1 = *reinterpret_cast<const short8_t*>(&Wt[(16 + lrow) * XS_STRIDE + 32 + lk]);
        c1 = __builtin_amdgcn_mfma_f32_16x16x32_bf16(a0, b0, c1, 0, 0, 0);
        c1 = __builtin_amdgcn_mfma_f32_16x16x32_bf16(a1, b1, c1, 0, 0, 0);
    }
    #pragma unroll
    for (int r = 0; r < 4; ++r) {
        int node = rowbase + wid * 16 + rq + r;
        if (node < n) {
            za[(size_t)node * 16 + lrow] = f2bf(c0[r] * dinva[node]);
            zb[(size_t)node * 16 + lrow] = f2bf(c1[r] * dinvb[node]);
        }
    }
}

// ---- fused dual-relation aggregation, layer 1 (bf16, F=64), h out bf16 ----
__global__ void __launch_bounds__(256, 8)
agg64_dual_kernel(const ushort_t* __restrict__ ya, const ushort_t* __restrict__ yb,
                  const int* __restrict__ rp2, const int* __restrict__ col2,
                  const float* __restrict__ dinv2,
                  const float* __restrict__ ba, const float* __restrict__ bb,
                  ushort_t* __restrict__ h, int n) {
    const int lane = threadIdx.x & 63;
    const int gw   = (blockIdx.x * blockDim.x + threadIdx.x) >> 6;
    const int nw   = (gridDim.x * blockDim.x) >> 6;
    const float bias = ba[lane] + bb[lane];
    for (int i = gw; i < n; i += nw) {
        const int e0a = rp2[i],     e1a = rp2[i + 1];
        const int e0b = rp2[n + i], e1b = rp2[n + i + 1];
        float acca = bf2f(ya[(size_t)i * 64 + lane]);
        float accb = bf2f(yb[(size_t)i * 64 + lane]);
        const int ma = min(64, e1a - e0a);
        const int mb = min(64, e1b - e0b);
        int cva = (lane < ma) ? col2[e0a + lane] : 0;
        int cvb = (lane < mb) ? col2[e0b + lane] : 0;
        const int mn = min(ma, mb);
        int j = 0;
        for (; j + 4 <= mn; j += 4) {
            int a0 = __shfl(cva, j),     b0 = __shfl(cvb, j);
            int a1 = __shfl(cva, j + 1), b1 = __shfl(cvb, j + 1);
            int a2 = __shfl(cva, j + 2), b2 = __shfl(cvb, j + 2);
            int a3 = __shfl(cva, j + 3), b3 = __shfl(cvb, j + 3);
            float ga0 = bf2f(ya[(size_t)a0 * 64 + lane]);
            float gb0 = bf2f(yb[(size_t)b0 * 64 + lane]);
            float ga1 = bf2f(ya[(size_t)a1 * 64 + lane]);
            float gb1 = bf2f(yb[(size_t)b1 * 64 + lane]);
            float ga2 = bf2f(ya[(size_t)a2 * 64 + lane]);
            float gb2 = bf2f(yb[(size_t)b2 * 64 + lane]);
            float ga3 = bf2f(ya[(size_t)a3 * 64 + lane]);
            float gb3 = bf2f(yb[(size_t)b3 * 64 + lane]);
            acca += (ga0 + ga1) + (ga2 + ga3);
            accb += (gb0 + gb1) + (gb2 + gb3);
        }
        for (; j < mn; ++j) {
            float ga = bf2f(ya[(size_t)__shfl(cva, j) * 64 + lane]);
            float gb = bf2f(yb[(size_t)__shfl(cvb, j) * 64 + lane]);
            acca += ga; accb += gb;
        }
        for (int ja = j; ja < ma; ++ja)
            acca += bf2f(ya[(size_t)__shfl(cva, ja) * 64 + lane]);
        for (int jb = j; jb < mb; ++jb)
            accb += bf2f(yb[(size_t)__shfl(cvb, jb) * 64 + lane]);
        for (int base = e0a + 64; base < e1a; base += 64) {
            const int m = min(64, e1a - base);
            int c = (lane < m) ? col2[base + lane] : 0;
            for (int jj = 0; jj < m; ++jj)
                acca += bf2f(ya[(size_t)__shfl(c, jj) * 64 + lane]);
        }
        for (int base = e0b + 64; base < e1b; base += 64) {
            const int m = min(64, e1b - base);
            int c = (lane < m) ? col2[base + lane] : 0;
            for (int jj = 0; jj < m; ++jj)
                accb += bf2f(yb[(size_t)__shfl(c, jj) * 64 + lane]);
        }
        float v = 0.5f * (acca * dinv2[i] + accb * dinv2[n + i] + bias);
        h[(size_t)i * 64 + lane] = f2bf(fmaxf(v, 0.0f));
    }
}

// ---- fused dual-relation aggregation, layer 2 (bf16, F=16) ----
__global__ void __launch_bounds__(256, 8)
agg16_dual_kernel(const ushort_t* __restrict__ za, const ushort_t* __restrict__ zb,
                  const int* __restrict__ rp2, const int* __restrict__ col2,
                  const float* __restrict__ dinv2,
                  const float* __restrict__ ba, const float* __restrict__ bb,
                  float* __restrict__ outp, int n) {
    const int lane = threadIdx.x & 63;
    const int f    = lane & 15;
    const int sub  = lane >> 4;
    const int gw   = (blockIdx.x * blockDim.x + threadIdx.x) >> 6;
    const int nw   = (gridDim.x * blockDim.x) >> 6;
    const float bias = ba[f] + bb[f];
    for (int i = gw; i < n; i += nw) {
        const int e1a = rp2[i + 1],     e1b = rp2[n + i + 1];
        int ea = rp2[i] + sub,          eb = rp2[n + i] + sub;
        float acca = (sub == 0) ? bf2f(za[(size_t)i * 16 + f]) : 0.0f;
        float accb = (sub == 0) ? bf2f(zb[(size_t)i * 16 + f]) : 0.0f;
        for (; ea + 4 < e1a && eb + 4 < e1b; ea += 8, eb += 8) {
            int c0 = col2[ea], c1 = col2[ea + 4];
            int d0 = col2[eb], d1 = col2[eb + 4];
            float g0 = bf2f(za[(size_t)c0 * 16 + f]);
            float g1 = bf2f(za[(size_t)c1 * 16 + f]);
            float g2 = bf2f(zb[(size_t)d0 * 16 + f]);
            float g3 = bf2f(zb[(size_t)d1 * 16 + f]);
            acca += g0 + g1;
            accb += g2 + g3;
        }
        for (; ea < e1a; ea += 4) acca += bf2f(za[(size_t)col2[ea] * 16 + f]);
        for (; eb < e1b; eb += 4) accb += bf2f(zb[(size_t)col2[eb] * 16 + f]);
        float v = acca * dinv2[i] + accb * dinv2[n + i];
        v += __shfl_xor(v, 16);
        v += __shfl_xor(v, 32);
        if (sub == 0) outp[(size_t)i * 16 + f] = 0.5f * (v + bias);
    }
}

extern "C" void kernel_launch(void* const* d_in, const int* in_sizes, int n_in,
                              void* d_out, int out_size, void* d_ws, size_t ws_size,
                              hipStream_t stream) {
    const float* x   = (const float*)d_in[0];
    const int*   eia = (const int*)d_in[1];
    const int*   eib = (const int*)d_in[2];
    const float* W1a = (const float*)d_in[3];
    const float* b1a = (const float*)d_in[4];
    const float* W1b = (const float*)d_in[5];
    const float* b1b = (const float*)d_in[6];
    const float* W2a = (const float*)d_in[7];
    const float* b2a = (const float*)d_in[8];
    const float* W2b = (const float*)d_in[9];
    const float* b2b = (const float*)d_in[10];
    float* out = (float*)d_out;

    const int n  = in_sizes[0] / 64;
    const int Ea = in_sizes[1] / 2;
    const int Eb = in_sizes[2] / 2;
    const int Et = Ea + Eb;
    const int n2 = 2 * n;

    int shift = 10;
    while ((((long long)n + (1LL << shift) - 1) >> shift) > 128) ++shift;
    const int nbuk = (int)(((long long)n + (1LL << shift) - 1) >> shift);
    const int nbuk2 = 2 * nbuk;

    char* wsp = (char*)d_ws;
    size_t off = 0;
    auto carve = [&](size_t elems) { void* p = wsp + off; off += ((elems + 3) & ~(size_t)3) * 4; return p; };
    float* dinv2    = (float*)carve(n2);
    int*   rowptr2  = (int*)carve(n2 + 1);
    int*   bcnt2    = (int*)carve(MAXBUK);
    int*   bbase2   = (int*)carve(MAXBUK);
    int*   bcursor2 = (int*)carve(MAXBUK);
    int*   col2     = (int*)carve(Et);
    ushort_t* ya    = (ushort_t*)carve((size_t)32 * n);   // 64n bf16
    ushort_t* yb    = (ushort_t*)carve((size_t)32 * n);
    ushort_t* za    = (ushort_t*)carve((size_t)8 * n);    // 16n bf16
    ushort_t* zb    = (ushort_t*)carve((size_t)8 * n);
    // big union: pairs (Et u32 words) dead after bucket_csr; then H (64n bf16 = 32n words)
    size_t big_words = (size_t)Et > (size_t)32 * n ? (size_t)Et : (size_t)32 * n;
    void*  big      = carve(big_words);
    uint_t* pairs   = (uint_t*)big;
    ushort_t* H     = (ushort_t*)big;

    const int T = 256;
    auto cdiv = [](long long a, long long b) { return (unsigned)((a + b - 1) / b); };

    // ---- combined CSR build ----
    zero_int_kernel<<<1, 256, 0, stream>>>(bcnt2, MAXBUK);
    bhist2_kernel<<<cdiv(Et, (long long)T * 16), T, 0, stream>>>(eia + Ea, eib + Eb, bcnt2,
                                                                 Ea, Et, shift, nbuk);
    bscan_kernel<<<1, 256, 0, stream>>>(bcnt2, bbase2, bcursor2, nbuk2, rowptr2, n2, Et);
    bfill2_kernel<<<cdiv(Et, BF_CHUNK), T, 0, stream>>>(eia, eib, bcursor2, pairs,
                                                        Ea, Eb, Et, shift, nbuk, n);
    if (shift == 10)
        bucket_csr_kernel<1024><<<nbuk2, 1024, 0, stream>>>(pairs, bbase2, bcnt2, rowptr2, dinv2,
                                                            col2, nbuk, shift, n);
    else if (shift == 11)
        bucket_csr_kernel<2048><<<nbuk2, 1024, 0, stream>>>(pairs, bbase2, bcnt2, rowptr2, dinv2,
                                                            col2, nbuk, shift, n);
    else
        bucket_csr_kernel<4096><<<nbuk2, 1024, 0, stream>>>(pairs, bbase2, bcnt2, rowptr2, dinv2,
                                                            col2, nbuk, shift, n);

    const unsigned AGG_GRID = 2048;

    // ---- layer 1 ----
    gemm2_mfma_bf16_kernel<<<cdiv(n, 64), T, 0, stream>>>(x, W1a, W1b, dinv2, dinv2 + n, ya, yb, n);
    agg64_dual_kernel<<<AGG_GRID, T, 0, stream>>>(ya, yb, rowptr2, col2, dinv2, b1a, b1b, H, n);

    // ---- layer 2 ----
    gemm2_mfma_h_kernel<<<cdiv(n, 64), T, 0, stream>>>(H, W2a, W2b, dinv2, dinv2 + n, za, zb, n);
    agg16_dual_kernel<<<AGG_GRID, T, 0, stream>>>(za, zb, rowptr2, col2, dinv2, b2a, b2b, out, n);
}

// Round 12
// 183.379 us; speedup vs baseline: 1.3219x; 1.2376x over previous
//
#include <hip/hip_runtime.h>

#define XS_STRIDE 72
#define MAXBUK 256
#define BF_CHUNK 4096

typedef unsigned short ushort_t;
typedef unsigned int uint_t;
typedef __attribute__((ext_vector_type(8))) short short8_t;
typedef __attribute__((ext_vector_type(4))) float f32x4;

__device__ __forceinline__ ushort_t f2bf(float x) {
    uint_t u = __float_as_uint(x);
    uint_t r = (u + 0x7FFFu + ((u >> 16) & 1u)) >> 16;
    return (ushort_t)r;
}
__device__ __forceinline__ float bf2f(ushort_t h) {
    return __uint_as_float((uint_t)h << 16);
}

// bcursor2[i] = i*CAP (fixed-capacity bucket bases)
__global__ void init_caps_kernel(int* bcursor2, int nbuk2, int CAP) {
    int i = blockIdx.x * blockDim.x + threadIdx.x;
    if (i < nbuk2) bcursor2[i] = i * CAP;
}

// Bin packed (src<<shift | dst_local) by combined bucket id; direct reservation
// into fixed-capacity buckets (no pre-count pass).
__global__ void bfill2_kernel(const int* __restrict__ eia, const int* __restrict__ eib,
                              int* __restrict__ bcursor, uint_t* __restrict__ pairs,
                              int Ea, int Eb, int Et, int shift, int nbuk, int n) {
    __shared__ int cnt[MAXBUK];
    __shared__ int base[MAXBUK];
    __shared__ int off[MAXBUK];
    const int t = threadIdx.x;
    const long long e0 = (long long)blockIdx.x * BF_CHUNK;
    const int nedge = (int)min((long long)BF_CHUNK, (long long)Et - e0);
    const int nbuk2 = 2 * nbuk;
    const uint_t mask = (1u << shift) - 1u;
    for (int i = t; i < nbuk2; i += 256) cnt[i] = 0;
    __syncthreads();
    for (int i = t; i < nedge; i += 256) {
        long long e = e0 + i;
        int rel = (e >= Ea);
        int d = rel ? eib[Eb + (e - Ea)] : eia[Ea + e];
        atomicAdd(&cnt[(rel ? nbuk : 0) + (d >> shift)], 1);
    }
    __syncthreads();
    for (int i = t; i < nbuk2; i += 256) {
        off[i] = 0;
        base[i] = cnt[i] ? atomicAdd(&bcursor[i], cnt[i]) : 0;
    }
    __syncthreads();
    for (int i = t; i < nedge; i += 256) {
        long long e = e0 + i;
        int rel = (e >= Ea);
        int s, d;
        if (rel) { s = eib[e - Ea]; d = eib[Eb + (e - Ea)]; }
        else     { s = eia[e];      d = eia[Ea + e]; }
        int b = (rel ? nbuk : 0) + (d >> shift);
        int p = base[b] + atomicAdd(&off[b], 1);
        pairs[p] = ((uint_t)s << shift) | ((uint_t)d & mask);
    }
}

// Per-bucket CSR build from packed pairs in fixed-capacity buckets.
// Writes per-node (start,end) = rowse2 (int2), dinv2, and col2 (gappy, bucket-local).
template<int NPB>
__global__ void bucket_csr_kernel(const uint_t* __restrict__ pairs,
                                  const int* __restrict__ bcursor2,
                                  int2* __restrict__ rowse2, float* __restrict__ dinv2,
                                  int* __restrict__ col2,
                                  int nbuk, int shift, int n, int CAP) {
    constexpr int BLK = 1024;
    constexpr int K = NPB / BLK;
    constexpr uint_t MASK = NPB - 1;
    __shared__ int cnt[NPB];
    __shared__ int wsum[16];
    const int b = blockIdx.x;
    const int t = threadIdx.x;
    const int lane = t & 63;
    const int w = t >> 6;
    const int rel = (b >= nbuk);
    const int blocal = rel ? b - nbuk : b;
    const int nodelo = blocal << shift;
    const int node0 = (rel ? n : 0) + nodelo;
    const int NN = min(NPB, n - nodelo);
    const int p0 = b * CAP;
    const int p1 = bcursor2[b];          // final cursor = base + count

    #pragma unroll
    for (int k = 0; k < K; ++k) cnt[t + k * BLK] = 0;
    __syncthreads();
    for (int idx = p0 + t; idx < p1; idx += BLK)
        atomicAdd(&cnt[pairs[idx] & MASK], 1);
    __syncthreads();

    int a[K]; int s = 0;
    #pragma unroll
    for (int k = 0; k < K; ++k) { a[k] = cnt[t * K + k]; s += a[k]; }
    int sc = s;
    #pragma unroll
    for (int d = 1; d < 64; d <<= 1) {
        int u = __shfl_up(sc, d);
        if (lane >= d) sc += u;
    }
    if (lane == 63) wsum[w] = sc;
    __syncthreads();
    if (t < 16) {
        int v = wsum[t];
        int scc = v;
        #pragma unroll
        for (int d = 1; d < 16; d <<= 1) {
            int u = __shfl_up(scc, d);
            if (t >= d) scc += u;
        }
        wsum[t] = scc - v;
    }
    __syncthreads();
    int run = p0 + wsum[w] + sc - s;
    __syncthreads();
    #pragma unroll
    for (int k = 0; k < K; ++k) {
        int j = t * K + k;
        cnt[j] = run;
        if (j < NN) {
            rowse2[node0 + j] = make_int2(run, run + a[k]);
            dinv2[node0 + j] = rsqrtf((float)(a[k] + 1));
        }
        run += a[k];
    }
    __syncthreads();
    for (int idx = p0 + t; idx < p1; idx += BLK) {
        uint_t p = pairs[idx];
        int pos = atomicAdd(&cnt[p & MASK], 1);
        col2[pos] = (int)(p >> shift);
    }
}

// ---- MFMA dual-weight GEMM (layer 1): ya|yb = (Xbf16 @ [Wa|Wb]) * dinv, bf16 out ----
__global__ void gemm2_mfma_bf16_kernel(const float* __restrict__ X,
                                       const float* __restrict__ Wa, const float* __restrict__ Wb,
                                       const float* __restrict__ dinva, const float* __restrict__ dinvb,
                                       ushort_t* __restrict__ ya, ushort_t* __restrict__ yb, int n) {
    __shared__ ushort_t Xs[64 * XS_STRIDE];
    __shared__ ushort_t Wt[128 * XS_STRIDE];
    const int tid = threadIdx.x;
    const int rowbase = blockIdx.x * 64;

    {
        int row = tid >> 2, cg = tid & 3;
        int grow = rowbase + row;
        float4 v[4];
        if (grow < n) {
            const float4* xr = reinterpret_cast<const float4*>(X + (size_t)grow * 64 + cg * 16);
            v[0] = xr[0]; v[1] = xr[1]; v[2] = xr[2]; v[3] = xr[3];
        } else {
            v[0] = v[1] = v[2] = v[3] = make_float4(0.f, 0.f, 0.f, 0.f);
        }
        ushort_t* dst = &Xs[row * XS_STRIDE + cg * 16];
        #pragma unroll
        for (int q = 0; q < 4; ++q) {
            dst[q * 4 + 0] = f2bf(v[q].x); dst[q * 4 + 1] = f2bf(v[q].y);
            dst[q * 4 + 2] = f2bf(v[q].z); dst[q * 4 + 3] = f2bf(v[q].w);
        }
    }
    for (int idx = tid; idx < 4096; idx += 256) {
        int k = idx >> 6, c = idx & 63;
        Wt[c * XS_STRIDE + k] = f2bf(Wa[idx]);
        Wt[(64 + c) * XS_STRIDE + k] = f2bf(Wb[idx]);
    }
    __syncthreads();

    const int wid = tid >> 6, lane = tid & 63;
    const int lrow = lane & 15;
    const int lk = (lane >> 4) * 8;

    short8_t a0 = *reinterpret_cast<const short8_t*>(&Xs[(wid * 16 + lrow) * XS_STRIDE + lk]);
    short8_t a1 = *reinterpret_cast<const short8_t*>(&Xs[(wid * 16 + lrow) * XS_STRIDE + 32 + lk]);

    f32x4 acc[8];
    #pragma unroll
    for (int ct = 0; ct < 8; ++ct) {
        short8_t b0 = *reinterpret_cast<const short8_t*>(&Wt[(ct * 16 + lrow) * XS_STRIDE + lk]);
        short8_t b1 = *reinterpret_cast<const short8_t*>(&Wt[(ct * 16 + lrow) * XS_STRIDE + 32 + lk]);
        f32x4 c = {0.f, 0.f, 0.f, 0.f};
        c = __builtin_amdgcn_mfma_f32_16x16x32_bf16(a0, b0, c, 0, 0, 0);
        c = __builtin_amdgcn_mfma_f32_16x16x32_bf16(a1, b1, c, 0, 0, 0);
        acc[ct] = c;
    }

    const int rq = (lane >> 4) * 4;
    #pragma unroll
    for (int r = 0; r < 4; ++r) {
        int grow = rowbase + wid * 16 + rq + r;
        if (grow < n) {
            float sa = dinva[grow], sb = dinvb[grow];
            #pragma unroll
            for (int ct = 0; ct < 8; ++ct) {
                int col = ct * 16 + lrow;
                float v = acc[ct][r];
                if (col < 64) ya[(size_t)grow * 64 + col] = f2bf(v * sa);
                else          yb[(size_t)grow * 64 + (col - 64)] = f2bf(v * sb);
            }
        }
    }
}

// ---- MFMA layer-2 GEMM: za|zb = (Hbf16 @ [W2a|W2b]) * dinv, bf16 out ----
__global__ void gemm2_mfma_h_kernel(const ushort_t* __restrict__ H,
                                    const float* __restrict__ W2a, const float* __restrict__ W2b,
                                    const float* __restrict__ dinva, const float* __restrict__ dinvb,
                                    ushort_t* __restrict__ za, ushort_t* __restrict__ zb, int n) {
    __shared__ ushort_t Hs[64 * XS_STRIDE];
    __shared__ ushort_t Wt[32 * XS_STRIDE];
    const int tid = threadIdx.x;
    const int rowbase = blockIdx.x * 64;

    {
        int row = tid >> 2, cg = tid & 3;
        int grow = rowbase + row;
        uint4 v0 = {0, 0, 0, 0}, v1 = {0, 0, 0, 0};
        if (grow < n) {
            const uint4* hr = reinterpret_cast<const uint4*>(H + (size_t)grow * 64 + cg * 16);
            v0 = hr[0]; v1 = hr[1];
        }
        uint4* dst = reinterpret_cast<uint4*>(&Hs[row * XS_STRIDE + cg * 16]);
        dst[0] = v0; dst[1] = v1;
    }
    for (int idx = tid; idx < 2048; idx += 256) {
        int c = idx & 31, k = idx >> 5;
        float v = (c < 16) ? W2a[k * 16 + c] : W2b[k * 16 + (c - 16)];
        Wt[c * XS_STRIDE + k] = f2bf(v);
    }
    __syncthreads();

    const int wid = tid >> 6, lane = tid & 63;
    const int lrow = lane & 15;
    const int lk = (lane >> 4) * 8;
    const int rq = (lane >> 4) * 4;

    short8_t a0 = *reinterpret_cast<const short8_t*>(&Hs[(wid * 16 + lrow) * XS_STRIDE + lk]);
    short8_t a1 = *reinterpret_cast<const short8_t*>(&Hs[(wid * 16 + lrow) * XS_STRIDE + 32 + lk]);

    f32x4 c0 = {0.f, 0.f, 0.f, 0.f}, c1 = {0.f, 0.f, 0.f, 0.f};
    {
        short8_t b0 = *reinterpret_cast<const short8_t*>(&Wt[lrow * XS_STRIDE + lk]);
        short8_t b1 = *reinterpret_cast<const short8_t*>(&Wt[lrow * XS_STRIDE + 32 + lk]);
        c0 = __builtin_amdgcn_mfma_f32_16x16x32_bf16(a0, b0, c0, 0, 0, 0);
        c0 = __builtin_amdgcn_mfma_f32_16x16x32_bf16(a1, b1, c0, 0, 0, 0);
    }
    {
        short8_t b0 = *reinterpret_cast<const short8_t*>(&Wt[(16 + lrow) * XS_STRIDE + lk]);
        short8_t b1 = *reinterpret_cast<const short8_t*>(&Wt[(16 + lrow) * XS_STRIDE + 32 + lk]);
        c1 = __builtin_amdgcn_mfma_f32_16x16x32_bf16(a0, b0, c1, 0, 0, 0);
        c1 = __builtin_amdgcn_mfma_f32_16x16x32_bf16(a1, b1, c1, 0, 0, 0);
    }
    #pragma unroll
    for (int r = 0; r < 4; ++r) {
        int node = rowbase + wid * 16 + rq + r;
        if (node < n) {
            za[(size_t)node * 16 + lrow] = f2bf(c0[r] * dinva[node]);
            zb[(size_t)node * 16 + lrow] = f2bf(c1[r] * dinvb[node]);
        }
    }
}

// ---- fused dual-relation aggregation, layer 1 (bf16, F=64), h out bf16 ----
__global__ void __launch_bounds__(256, 8)
agg64_dual_kernel(const ushort_t* __restrict__ ya, const ushort_t* __restrict__ yb,
                  const int2* __restrict__ rowse2, const int* __restrict__ col2,
                  const float* __restrict__ dinv2,
                  const float* __restrict__ ba, const float* __restrict__ bb,
                  ushort_t* __restrict__ h, int n) {
    const int lane = threadIdx.x & 63;
    const int gw   = (blockIdx.x * blockDim.x + threadIdx.x) >> 6;
    const int nw   = (gridDim.x * blockDim.x) >> 6;
    const float bias = ba[lane] + bb[lane];
    for (int i = gw; i < n; i += nw) {
        const int2 sea = rowse2[i];
        const int2 seb = rowse2[n + i];
        const int e0a = sea.x, e1a = sea.y;
        const int e0b = seb.x, e1b = seb.y;
        float acca = bf2f(ya[(size_t)i * 64 + lane]);
        float accb = bf2f(yb[(size_t)i * 64 + lane]);
        const int ma = min(64, e1a - e0a);
        const int mb = min(64, e1b - e0b);
        int cva = (lane < ma) ? col2[e0a + lane] : 0;
        int cvb = (lane < mb) ? col2[e0b + lane] : 0;
        const int mn = min(ma, mb);
        int j = 0;
        for (; j + 4 <= mn; j += 4) {
            int a0 = __shfl(cva, j),     b0 = __shfl(cvb, j);
            int a1 = __shfl(cva, j + 1), b1 = __shfl(cvb, j + 1);
            int a2 = __shfl(cva, j + 2), b2 = __shfl(cvb, j + 2);
            int a3 = __shfl(cva, j + 3), b3 = __shfl(cvb, j + 3);
            float ga0 = bf2f(ya[(size_t)a0 * 64 + lane]);
            float gb0 = bf2f(yb[(size_t)b0 * 64 + lane]);
            float ga1 = bf2f(ya[(size_t)a1 * 64 + lane]);
            float gb1 = bf2f(yb[(size_t)b1 * 64 + lane]);
            float ga2 = bf2f(ya[(size_t)a2 * 64 + lane]);
            float gb2 = bf2f(yb[(size_t)b2 * 64 + lane]);
            float ga3 = bf2f(ya[(size_t)a3 * 64 + lane]);
            float gb3 = bf2f(yb[(size_t)b3 * 64 + lane]);
            acca += (ga0 + ga1) + (ga2 + ga3);
            accb += (gb0 + gb1) + (gb2 + gb3);
        }
        for (; j < mn; ++j) {
            float ga = bf2f(ya[(size_t)__shfl(cva, j) * 64 + lane]);
            float gb = bf2f(yb[(size_t)__shfl(cvb, j) * 64 + lane]);
            acca += ga; accb += gb;
        }
        for (int ja = j; ja < ma; ++ja)
            acca += bf2f(ya[(size_t)__shfl(cva, ja) * 64 + lane]);
        for (int jb = j; jb < mb; ++jb)
            accb += bf2f(yb[(size_t)__shfl(cvb, jb) * 64 + lane]);
        for (int base = e0a + 64; base < e1a; base += 64) {
            const int m = min(64, e1a - base);
            int c = (lane < m) ? col2[base + lane] : 0;
            for (int jj = 0; jj < m; ++jj)
                acca += bf2f(ya[(size_t)__shfl(c, jj) * 64 + lane]);
        }
        for (int base = e0b + 64; base < e1b; base += 64) {
            const int m = min(64, e1b - base);
            int c = (lane < m) ? col2[base + lane] : 0;
            for (int jj = 0; jj < m; ++jj)
                accb += bf2f(yb[(size_t)__shfl(c, jj) * 64 + lane]);
        }
        float v = 0.5f * (acca * dinv2[i] + accb * dinv2[n + i] + bias);
        h[(size_t)i * 64 + lane] = f2bf(fmaxf(v, 0.0f));
    }
}

// ---- fused dual-relation aggregation, layer 2 (bf16, F=16) ----
__global__ void __launch_bounds__(256, 8)
agg16_dual_kernel(const ushort_t* __restrict__ za, const ushort_t* __restrict__ zb,
                  const int2* __restrict__ rowse2, const int* __restrict__ col2,
                  const float* __restrict__ dinv2,
                  const float* __restrict__ ba, const float* __restrict__ bb,
                  float* __restrict__ outp, int n) {
    const int lane = threadIdx.x & 63;
    const int f    = lane & 15;
    const int sub  = lane >> 4;
    const int gw   = (blockIdx.x * blockDim.x + threadIdx.x) >> 6;
    const int nw   = (gridDim.x * blockDim.x) >> 6;
    const float bias = ba[f] + bb[f];
    for (int i = gw; i < n; i += nw) {
        const int2 sea = rowse2[i];
        const int2 seb = rowse2[n + i];
        int ea = sea.x + sub, eb = seb.x + sub;
        const int e1a = sea.y, e1b = seb.y;
        float acca = (sub == 0) ? bf2f(za[(size_t)i * 16 + f]) : 0.0f;
        float accb = (sub == 0) ? bf2f(zb[(size_t)i * 16 + f]) : 0.0f;
        for (; ea + 4 < e1a && eb + 4 < e1b; ea += 8, eb += 8) {
            int c0 = col2[ea], c1 = col2[ea + 4];
            int d0 = col2[eb], d1 = col2[eb + 4];
            float g0 = bf2f(za[(size_t)c0 * 16 + f]);
            float g1 = bf2f(za[(size_t)c1 * 16 + f]);
            float g2 = bf2f(zb[(size_t)d0 * 16 + f]);
            float g3 = bf2f(zb[(size_t)d1 * 16 + f]);
            acca += g0 + g1;
            accb += g2 + g3;
        }
        for (; ea < e1a; ea += 4) acca += bf2f(za[(size_t)col2[ea] * 16 + f]);
        for (; eb < e1b; eb += 4) accb += bf2f(zb[(size_t)col2[eb] * 16 + f]);
        float v = acca * dinv2[i] + accb * dinv2[n + i];
        v += __shfl_xor(v, 16);
        v += __shfl_xor(v, 32);
        if (sub == 0) outp[(size_t)i * 16 + f] = 0.5f * (v + bias);
    }
}

extern "C" void kernel_launch(void* const* d_in, const int* in_sizes, int n_in,
                              void* d_out, int out_size, void* d_ws, size_t ws_size,
                              hipStream_t stream) {
    const float* x   = (const float*)d_in[0];
    const int*   eia = (const int*)d_in[1];
    const int*   eib = (const int*)d_in[2];
    const float* W1a = (const float*)d_in[3];
    const float* b1a = (const float*)d_in[4];
    const float* W1b = (const float*)d_in[5];
    const float* b1b = (const float*)d_in[6];
    const float* W2a = (const float*)d_in[7];
    const float* b2a = (const float*)d_in[8];
    const float* W2b = (const float*)d_in[9];
    const float* b2b = (const float*)d_in[10];
    float* out = (float*)d_out;

    const int n  = in_sizes[0] / 64;
    const int Ea = in_sizes[1] / 2;
    const int Eb = in_sizes[2] / 2;
    const int Et = Ea + Eb;
    const int n2 = 2 * n;

    int shift = 10;
    while ((((long long)n + (1LL << shift) - 1) >> shift) > 128) ++shift;
    const int nbuk = (int)(((long long)n + (1LL << shift) - 1) >> shift);
    const int nbuk2 = 2 * nbuk;
    // fixed bucket capacity: 1.5x mean + 2048 slack (>>20 sigma for uniform-random edges)
    const int Emaxrel = Ea > Eb ? Ea : Eb;
    int CAP = ((Emaxrel / (nbuk > 0 ? nbuk : 1)) * 3) / 2 + 2048;
    CAP = (CAP + 63) & ~63;

    char* wsp = (char*)d_ws;
    size_t off = 0;
    auto carve = [&](size_t elems) { void* p = wsp + off; off += ((elems + 3) & ~(size_t)3) * 4; return p; };
    float* dinv2    = (float*)carve(n2);
    int2*  rowse2   = (int2*)carve((size_t)n2 * 2);
    int*   bcursor2 = (int*)carve(MAXBUK);
    int*   col2     = (int*)carve((size_t)nbuk2 * CAP);
    ushort_t* ya    = (ushort_t*)carve((size_t)32 * n);   // 64n bf16
    ushort_t* yb    = (ushort_t*)carve((size_t)32 * n);
    ushort_t* za    = (ushort_t*)carve((size_t)8 * n);    // 16n bf16
    ushort_t* zb    = (ushort_t*)carve((size_t)8 * n);
    // big union: pairs (nbuk2*CAP u32 words) dead after bucket_csr; then H (64n bf16 = 32n words)
    size_t pair_words = (size_t)nbuk2 * CAP;
    size_t big_words = pair_words > (size_t)32 * n ? pair_words : (size_t)32 * n;
    void*  big      = carve(big_words);
    uint_t* pairs   = (uint_t*)big;
    ushort_t* H     = (ushort_t*)big;

    const int T = 256;
    auto cdiv = [](long long a, long long b) { return (unsigned)((a + b - 1) / b); };

    // ---- combined CSR build (no pre-count pass) ----
    init_caps_kernel<<<1, 256, 0, stream>>>(bcursor2, nbuk2, CAP);
    bfill2_kernel<<<cdiv(Et, BF_CHUNK), T, 0, stream>>>(eia, eib, bcursor2, pairs,
                                                        Ea, Eb, Et, shift, nbuk, n);
    if (shift == 10)
        bucket_csr_kernel<1024><<<nbuk2, 1024, 0, stream>>>(pairs, bcursor2, rowse2, dinv2,
                                                            col2, nbuk, shift, n, CAP);
    else if (shift == 11)
        bucket_csr_kernel<2048><<<nbuk2, 1024, 0, stream>>>(pairs, bcursor2, rowse2, dinv2,
                                                            col2, nbuk, shift, n, CAP);
    else
        bucket_csr_kernel<4096><<<nbuk2, 1024, 0, stream>>>(pairs, bcursor2, rowse2, dinv2,
                                                            col2, nbuk, shift, n, CAP);

    const unsigned AGG_GRID = 2048;

    // ---- layer 1 ----
    gemm2_mfma_bf16_kernel<<<cdiv(n, 64), T, 0, stream>>>(x, W1a, W1b, dinv2, dinv2 + n, ya, yb, n);
    agg64_dual_kernel<<<AGG_GRID, T, 0, stream>>>(ya, yb, rowse2, col2, dinv2, b1a, b1b, H, n);

    // ---- layer 2 ----
    gemm2_mfma_h_kernel<<<cdiv(n, 64), T, 0, stream>>>(H, W2a, W2b, dinv2, dinv2 + n, za, zb, n);
    agg16_dual_kernel<<<AGG_GRID, T, 0, stream>>>(za, zb, rowse2, col2, dinv2, b2a, b2b, out, n);
}

// Round 13
// 168.243 us; speedup vs baseline: 1.4408x; 1.0900x over previous
//
#include <hip/hip_runtime.h>

#define XS_STRIDE 72
#define MAXBUK 256
#define BF_CHUNK 4096

typedef unsigned short ushort_t;
typedef unsigned int uint_t;
typedef __attribute__((ext_vector_type(8))) short short8_t;
typedef __attribute__((ext_vector_type(4))) float f32x4;

__device__ __forceinline__ ushort_t f2bf(float x) {
    uint_t u = __float_as_uint(x);
    uint_t r = (u + 0x7FFFu + ((u >> 16) & 1u)) >> 16;
    return (ushort_t)r;
}
__device__ __forceinline__ float bf2f(ushort_t h) {
    return __uint_as_float((uint_t)h << 16);
}
__device__ __forceinline__ float bf2f_lo(uint_t g) { return __uint_as_float(g << 16); }
__device__ __forceinline__ float bf2f_hi(uint_t g) { return __uint_as_float(g & 0xFFFF0000u); }

// bcursor2[i] = i*CAP (fixed-capacity bucket bases)
__global__ void init_caps_kernel(int* bcursor2, int nbuk2, int CAP) {
    int i = blockIdx.x * blockDim.x + threadIdx.x;
    if (i < nbuk2) bcursor2[i] = i * CAP;
}

// Bin packed (src<<shift | dst_local) by combined bucket id; direct reservation
// into fixed-capacity buckets (no pre-count pass).
__global__ void bfill2_kernel(const int* __restrict__ eia, const int* __restrict__ eib,
                              int* __restrict__ bcursor, uint_t* __restrict__ pairs,
                              int Ea, int Eb, int Et, int shift, int nbuk, int n) {
    __shared__ int cnt[MAXBUK];
    __shared__ int base[MAXBUK];
    __shared__ int off[MAXBUK];
    const int t = threadIdx.x;
    const long long e0 = (long long)blockIdx.x * BF_CHUNK;
    const int nedge = (int)min((long long)BF_CHUNK, (long long)Et - e0);
    const int nbuk2 = 2 * nbuk;
    const uint_t mask = (1u << shift) - 1u;
    for (int i = t; i < nbuk2; i += 256) cnt[i] = 0;
    __syncthreads();
    for (int i = t; i < nedge; i += 256) {
        long long e = e0 + i;
        int rel = (e >= Ea);
        int d = rel ? eib[Eb + (e - Ea)] : eia[Ea + e];
        atomicAdd(&cnt[(rel ? nbuk : 0) + (d >> shift)], 1);
    }
    __syncthreads();
    for (int i = t; i < nbuk2; i += 256) {
        off[i] = 0;
        base[i] = cnt[i] ? atomicAdd(&bcursor[i], cnt[i]) : 0;
    }
    __syncthreads();
    for (int i = t; i < nedge; i += 256) {
        long long e = e0 + i;
        int rel = (e >= Ea);
        int s, d;
        if (rel) { s = eib[e - Ea]; d = eib[Eb + (e - Ea)]; }
        else     { s = eia[e];      d = eia[Ea + e]; }
        int b = (rel ? nbuk : 0) + (d >> shift);
        int p = base[b] + atomicAdd(&off[b], 1);
        pairs[p] = ((uint_t)s << shift) | ((uint_t)d & mask);
    }
}

// Per-bucket CSR build from packed pairs in fixed-capacity buckets.
template<int NPB>
__global__ void bucket_csr_kernel(const uint_t* __restrict__ pairs,
                                  const int* __restrict__ bcursor2,
                                  int2* __restrict__ rowse2, float* __restrict__ dinv2,
                                  int* __restrict__ col2,
                                  int nbuk, int shift, int n, int CAP) {
    constexpr int BLK = 1024;
    constexpr int K = NPB / BLK;
    constexpr uint_t MASK = NPB - 1;
    __shared__ int cnt[NPB];
    __shared__ int wsum[16];
    const int b = blockIdx.x;
    const int t = threadIdx.x;
    const int lane = t & 63;
    const int w = t >> 6;
    const int rel = (b >= nbuk);
    const int blocal = rel ? b - nbuk : b;
    const int nodelo = blocal << shift;
    const int node0 = (rel ? n : 0) + nodelo;
    const int NN = min(NPB, n - nodelo);
    const int p0 = b * CAP;
    const int p1 = bcursor2[b];

    #pragma unroll
    for (int k = 0; k < K; ++k) cnt[t + k * BLK] = 0;
    __syncthreads();
    for (int idx = p0 + t; idx < p1; idx += BLK)
        atomicAdd(&cnt[pairs[idx] & MASK], 1);
    __syncthreads();

    int a[K]; int s = 0;
    #pragma unroll
    for (int k = 0; k < K; ++k) { a[k] = cnt[t * K + k]; s += a[k]; }
    int sc = s;
    #pragma unroll
    for (int d = 1; d < 64; d <<= 1) {
        int u = __shfl_up(sc, d);
        if (lane >= d) sc += u;
    }
    if (lane == 63) wsum[w] = sc;
    __syncthreads();
    if (t < 16) {
        int v = wsum[t];
        int scc = v;
        #pragma unroll
        for (int d = 1; d < 16; d <<= 1) {
            int u = __shfl_up(scc, d);
            if (t >= d) scc += u;
        }
        wsum[t] = scc - v;
    }
    __syncthreads();
    int run = p0 + wsum[w] + sc - s;
    __syncthreads();
    #pragma unroll
    for (int k = 0; k < K; ++k) {
        int j = t * K + k;
        cnt[j] = run;
        if (j < NN) {
            rowse2[node0 + j] = make_int2(run, run + a[k]);
            dinv2[node0 + j] = rsqrtf((float)(a[k] + 1));
        }
        run += a[k];
    }
    __syncthreads();
    for (int idx = p0 + t; idx < p1; idx += BLK) {
        uint_t p = pairs[idx];
        int pos = atomicAdd(&cnt[p & MASK], 1);
        col2[pos] = (int)(p >> shift);
    }
}

// ---- MFMA dual-weight GEMM (layer 1): ya|yb = (Xbf16 @ [Wa|Wb]) * dinv, bf16 out ----
__global__ void gemm2_mfma_bf16_kernel(const float* __restrict__ X,
                                       const float* __restrict__ Wa, const float* __restrict__ Wb,
                                       const float* __restrict__ dinva, const float* __restrict__ dinvb,
                                       ushort_t* __restrict__ ya, ushort_t* __restrict__ yb, int n) {
    __shared__ ushort_t Xs[64 * XS_STRIDE];
    __shared__ ushort_t Wt[128 * XS_STRIDE];
    const int tid = threadIdx.x;
    const int rowbase = blockIdx.x * 64;

    {
        int row = tid >> 2, cg = tid & 3;
        int grow = rowbase + row;
        float4 v[4];
        if (grow < n) {
            const float4* xr = reinterpret_cast<const float4*>(X + (size_t)grow * 64 + cg * 16);
            v[0] = xr[0]; v[1] = xr[1]; v[2] = xr[2]; v[3] = xr[3];
        } else {
            v[0] = v[1] = v[2] = v[3] = make_float4(0.f, 0.f, 0.f, 0.f);
        }
        ushort_t* dst = &Xs[row * XS_STRIDE + cg * 16];
        #pragma unroll
        for (int q = 0; q < 4; ++q) {
            dst[q * 4 + 0] = f2bf(v[q].x); dst[q * 4 + 1] = f2bf(v[q].y);
            dst[q * 4 + 2] = f2bf(v[q].z); dst[q * 4 + 3] = f2bf(v[q].w);
        }
    }
    for (int idx = tid; idx < 4096; idx += 256) {
        int k = idx >> 6, c = idx & 63;
        Wt[c * XS_STRIDE + k] = f2bf(Wa[idx]);
        Wt[(64 + c) * XS_STRIDE + k] = f2bf(Wb[idx]);
    }
    __syncthreads();

    const int wid = tid >> 6, lane = tid & 63;
    const int lrow = lane & 15;
    const int lk = (lane >> 4) * 8;

    short8_t a0 = *reinterpret_cast<const short8_t*>(&Xs[(wid * 16 + lrow) * XS_STRIDE + lk]);
    short8_t a1 = *reinterpret_cast<const short8_t*>(&Xs[(wid * 16 + lrow) * XS_STRIDE + 32 + lk]);

    f32x4 acc[8];
    #pragma unroll
    for (int ct = 0; ct < 8; ++ct) {
        short8_t b0 = *reinterpret_cast<const short8_t*>(&Wt[(ct * 16 + lrow) * XS_STRIDE + lk]);
        short8_t b1 = *reinterpret_cast<const short8_t*>(&Wt[(ct * 16 + lrow) * XS_STRIDE + 32 + lk]);
        f32x4 c = {0.f, 0.f, 0.f, 0.f};
        c = __builtin_amdgcn_mfma_f32_16x16x32_bf16(a0, b0, c, 0, 0, 0);
        c = __builtin_amdgcn_mfma_f32_16x16x32_bf16(a1, b1, c, 0, 0, 0);
        acc[ct] = c;
    }

    const int rq = (lane >> 4) * 4;
    #pragma unroll
    for (int r = 0; r < 4; ++r) {
        int grow = rowbase + wid * 16 + rq + r;
        if (grow < n) {
            float sa = dinva[grow], sb = dinvb[grow];
            #pragma unroll
            for (int ct = 0; ct < 8; ++ct) {
                int col = ct * 16 + lrow;
                float v = acc[ct][r];
                if (col < 64) ya[(size_t)grow * 64 + col] = f2bf(v * sa);
                else          yb[(size_t)grow * 64 + (col - 64)] = f2bf(v * sb);
            }
        }
    }
}

// ---- MFMA layer-2 GEMM: za|zb = (Hbf16 @ [W2a|W2b]) * dinv, bf16 out ----
__global__ void gemm2_mfma_h_kernel(const ushort_t* __restrict__ H,
                                    const float* __restrict__ W2a, const float* __restrict__ W2b,
                                    const float* __restrict__ dinva, const float* __restrict__ dinvb,
                                    ushort_t* __restrict__ za, ushort_t* __restrict__ zb, int n) {
    __shared__ ushort_t Hs[64 * XS_STRIDE];
    __shared__ ushort_t Wt[32 * XS_STRIDE];
    const int tid = threadIdx.x;
    const int rowbase = blockIdx.x * 64;

    {
        int row = tid >> 2, cg = tid & 3;
        int grow = rowbase + row;
        uint4 v0 = {0, 0, 0, 0}, v1 = {0, 0, 0, 0};
        if (grow < n) {
            const uint4* hr = reinterpret_cast<const uint4*>(H + (size_t)grow * 64 + cg * 16);
            v0 = hr[0]; v1 = hr[1];
        }
        uint4* dst = reinterpret_cast<uint4*>(&Hs[row * XS_STRIDE + cg * 16]);
        dst[0] = v0; dst[1] = v1;
    }
    for (int idx = tid; idx < 2048; idx += 256) {
        int c = idx & 31, k = idx >> 5;
        float v = (c < 16) ? W2a[k * 16 + c] : W2b[k * 16 + (c - 16)];
        Wt[c * XS_STRIDE + k] = f2bf(v);
    }
    __syncthreads();

    const int wid = tid >> 6, lane = tid & 63;
    const int lrow = lane & 15;
    const int lk = (lane >> 4) * 8;
    const int rq = (lane >> 4) * 4;

    short8_t a0 = *reinterpret_cast<const short8_t*>(&Hs[(wid * 16 + lrow) * XS_STRIDE + lk]);
    short8_t a1 = *reinterpret_cast<const short8_t*>(&Hs[(wid * 16 + lrow) * XS_STRIDE + 32 + lk]);

    f32x4 c0 = {0.f, 0.f, 0.f, 0.f}, c1 = {0.f, 0.f, 0.f, 0.f};
    {
        short8_t b0 = *reinterpret_cast<const short8_t*>(&Wt[lrow * XS_STRIDE + lk]);
        short8_t b1 = *reinterpret_cast<const short8_t*>(&Wt[lrow * XS_STRIDE + 32 + lk]);
        c0 = __builtin_amdgcn_mfma_f32_16x16x32_bf16(a0, b0, c0, 0, 0, 0);
        c0 = __builtin_amdgcn_mfma_f32_16x16x32_bf16(a1, b1, c0, 0, 0, 0);
    }
    {
        short8_t b0 = *reinterpret_cast<const short8_t*>(&Wt[(16 + lrow) * XS_STRIDE + lk]);
        short8_t b1 = *reinterpret_cast<const short8_t*>(&Wt[(16 + lrow) * XS_STRIDE + 32 + lk]);
        c1 = __builtin_amdgcn_mfma_f32_16x16x32_bf16(a0, b0, c1, 0, 0, 0);
        c1 = __builtin_amdgcn_mfma_f32_16x16x32_bf16(a1, b1, c1, 0, 0, 0);
    }
    #pragma unroll
    for (int r = 0; r < 4; ++r) {
        int node = rowbase + wid * 16 + rq + r;
        if (node < n) {
            za[(size_t)node * 16 + lrow] = f2bf(c0[r] * dinva[node]);
            zb[(size_t)node * 16 + lrow] = f2bf(c1[r] * dinvb[node]);
        }
    }
}

// ---- fused dual-relation aggregation, layer 1 (bf16, F=64), h out bf16 ----
// Double-width lanes: lane = (half, feat-pair); one VMEM instruction = 2 edges.
__global__ void __launch_bounds__(256, 8)
agg64_dual_kernel(const ushort_t* __restrict__ ya, const ushort_t* __restrict__ yb,
                  const int2* __restrict__ rowse2, const int* __restrict__ col2,
                  const float* __restrict__ dinv2,
                  const float* __restrict__ ba, const float* __restrict__ bb,
                  ushort_t* __restrict__ h, int n) {
    const int lane = threadIdx.x & 63;
    const int half = lane >> 5;        // edge parity handled by this lane
    const int fp   = lane & 31;        // feature pair: feats 2fp, 2fp+1
    const int gw   = (blockIdx.x * blockDim.x + threadIdx.x) >> 6;
    const int nw   = (gridDim.x * blockDim.x) >> 6;
    const float bx = ba[2 * fp] + bb[2 * fp];
    const float by = ba[2 * fp + 1] + bb[2 * fp + 1];
    for (int i = gw; i < n; i += nw) {
        const int2 sea = rowse2[i];
        const int2 seb = rowse2[n + i];
        float ax = 0.f, ay = 0.f, bx2 = 0.f, by2 = 0.f;
        if (half == 0) {   // self terms counted once
            uint_t ga = *reinterpret_cast<const uint_t*>(ya + (size_t)i * 64 + 2 * fp);
            uint_t gb = *reinterpret_cast<const uint_t*>(yb + (size_t)i * 64 + 2 * fp);
            ax = bf2f_lo(ga); ay = bf2f_hi(ga);
            bx2 = bf2f_lo(gb); by2 = bf2f_hi(gb);
        }
        // relation a
        for (int base0 = sea.x; base0 < sea.y; base0 += 64) {
            const int m = min(64, sea.y - base0);
            int cv = (lane < m) ? col2[base0 + lane] : 0;
            int j = 0;
            for (; j + 8 <= m; j += 8) {
                int c0 = __shfl(cv, j + half),     c1 = __shfl(cv, j + 2 + half);
                int c2 = __shfl(cv, j + 4 + half), c3 = __shfl(cv, j + 6 + half);
                uint_t g0 = *reinterpret_cast<const uint_t*>(ya + (size_t)c0 * 64 + 2 * fp);
                uint_t g1 = *reinterpret_cast<const uint_t*>(ya + (size_t)c1 * 64 + 2 * fp);
                uint_t g2 = *reinterpret_cast<const uint_t*>(ya + (size_t)c2 * 64 + 2 * fp);
                uint_t g3 = *reinterpret_cast<const uint_t*>(ya + (size_t)c3 * 64 + 2 * fp);
                ax += (bf2f_lo(g0) + bf2f_lo(g1)) + (bf2f_lo(g2) + bf2f_lo(g3));
                ay += (bf2f_hi(g0) + bf2f_hi(g1)) + (bf2f_hi(g2) + bf2f_hi(g3));
            }
            for (; j + 2 <= m; j += 2) {
                int c = __shfl(cv, j + half);
                uint_t g = *reinterpret_cast<const uint_t*>(ya + (size_t)c * 64 + 2 * fp);
                ax += bf2f_lo(g); ay += bf2f_hi(g);
            }
            if (j < m) {
                int c = __shfl(cv, j);
                if (half == 0) {
                    uint_t g = *reinterpret_cast<const uint_t*>(ya + (size_t)c * 64 + 2 * fp);
                    ax += bf2f_lo(g); ay += bf2f_hi(g);
                }
            }
        }
        // relation b
        for (int base0 = seb.x; base0 < seb.y; base0 += 64) {
            const int m = min(64, seb.y - base0);
            int cv = (lane < m) ? col2[base0 + lane] : 0;
            int j = 0;
            for (; j + 8 <= m; j += 8) {
                int c0 = __shfl(cv, j + half),     c1 = __shfl(cv, j + 2 + half);
                int c2 = __shfl(cv, j + 4 + half), c3 = __shfl(cv, j + 6 + half);
                uint_t g0 = *reinterpret_cast<const uint_t*>(yb + (size_t)c0 * 64 + 2 * fp);
                uint_t g1 = *reinterpret_cast<const uint_t*>(yb + (size_t)c1 * 64 + 2 * fp);
                uint_t g2 = *reinterpret_cast<const uint_t*>(yb + (size_t)c2 * 64 + 2 * fp);
                uint_t g3 = *reinterpret_cast<const uint_t*>(yb + (size_t)c3 * 64 + 2 * fp);
                bx2 += (bf2f_lo(g0) + bf2f_lo(g1)) + (bf2f_lo(g2) + bf2f_lo(g3));
                by2 += (bf2f_hi(g0) + bf2f_hi(g1)) + (bf2f_hi(g2) + bf2f_hi(g3));
            }
            for (; j + 2 <= m; j += 2) {
                int c = __shfl(cv, j + half);
                uint_t g = *reinterpret_cast<const uint_t*>(yb + (size_t)c * 64 + 2 * fp);
                bx2 += bf2f_lo(g); by2 += bf2f_hi(g);
            }
            if (j < m) {
                int c = __shfl(cv, j);
                if (half == 0) {
                    uint_t g = *reinterpret_cast<const uint_t*>(yb + (size_t)c * 64 + 2 * fp);
                    bx2 += bf2f_lo(g); by2 += bf2f_hi(g);
                }
            }
        }
        // merge the two halves (lane l <-> l^32 hold same feature pair)
        ax += __shfl_xor(ax, 32);  ay += __shfl_xor(ay, 32);
        bx2 += __shfl_xor(bx2, 32); by2 += __shfl_xor(by2, 32);
        const float da = dinv2[i], db = dinv2[n + i];
        if (half == 0) {
            float vx = fmaxf(0.5f * (ax * da + bx2 * db + bx), 0.0f);
            float vy = fmaxf(0.5f * (ay * da + by2 * db + by), 0.0f);
            uint_t p = (uint_t)f2bf(vx) | ((uint_t)f2bf(vy) << 16);
            *reinterpret_cast<uint_t*>(h + (size_t)i * 64 + 2 * fp) = p;
        }
    }
}

// ---- fused dual-relation aggregation, layer 2 (bf16, F=16) ----
// Double-width lanes: lane = (8 edge-slots, 8 feat-pairs); one instruction = 8 edges.
__global__ void __launch_bounds__(256, 8)
agg16_dual_kernel(const ushort_t* __restrict__ za, const ushort_t* __restrict__ zb,
                  const int2* __restrict__ rowse2, const int* __restrict__ col2,
                  const float* __restrict__ dinv2,
                  const float* __restrict__ ba, const float* __restrict__ bb,
                  float* __restrict__ outp, int n) {
    const int lane = threadIdx.x & 63;
    const int fp   = lane & 7;        // feats 2fp, 2fp+1
    const int sub  = lane >> 3;       // 0..7 edge slots
    const int gw   = (blockIdx.x * blockDim.x + threadIdx.x) >> 6;
    const int nw   = (gridDim.x * blockDim.x) >> 6;
    const float bx = ba[2 * fp] + bb[2 * fp];
    const float by = ba[2 * fp + 1] + bb[2 * fp + 1];
    for (int i = gw; i < n; i += nw) {
        const int2 sea = rowse2[i];
        const int2 seb = rowse2[n + i];
        int ea = sea.x + sub, eb = seb.x + sub;
        const int e1a = sea.y, e1b = seb.y;
        float ax = 0.f, ay = 0.f, bx2 = 0.f, by2 = 0.f;
        if (sub == 0) {
            uint_t ga = *reinterpret_cast<const uint_t*>(za + (size_t)i * 16 + 2 * fp);
            uint_t gb = *reinterpret_cast<const uint_t*>(zb + (size_t)i * 16 + 2 * fp);
            ax = bf2f_lo(ga); ay = bf2f_hi(ga);
            bx2 = bf2f_lo(gb); by2 = bf2f_hi(gb);
        }
        for (; ea + 8 < e1a && eb + 8 < e1b; ea += 16, eb += 16) {
            int c0 = col2[ea], c1 = col2[ea + 8];
            int d0 = col2[eb], d1 = col2[eb + 8];
            uint_t g0 = *reinterpret_cast<const uint_t*>(za + (size_t)c0 * 16 + 2 * fp);
            uint_t g1 = *reinterpret_cast<const uint_t*>(za + (size_t)c1 * 16 + 2 * fp);
            uint_t g2 = *reinterpret_cast<const uint_t*>(zb + (size_t)d0 * 16 + 2 * fp);
            uint_t g3 = *reinterpret_cast<const uint_t*>(zb + (size_t)d1 * 16 + 2 * fp);
            ax += bf2f_lo(g0) + bf2f_lo(g1);  ay += bf2f_hi(g0) + bf2f_hi(g1);
            bx2 += bf2f_lo(g2) + bf2f_lo(g3); by2 += bf2f_hi(g2) + bf2f_hi(g3);
        }
        for (; ea < e1a; ea += 8) {
            uint_t g = *reinterpret_cast<const uint_t*>(za + (size_t)col2[ea] * 16 + 2 * fp);
            ax += bf2f_lo(g); ay += bf2f_hi(g);
        }
        for (; eb < e1b; eb += 8) {
            uint_t g = *reinterpret_cast<const uint_t*>(zb + (size_t)col2[eb] * 16 + 2 * fp);
            bx2 += bf2f_lo(g); by2 += bf2f_hi(g);
        }
        const float da = dinv2[i], db = dinv2[n + i];
        float vx = ax * da + bx2 * db;
        float vy = ay * da + by2 * db;
        vx += __shfl_xor(vx, 8);  vy += __shfl_xor(vy, 8);
        vx += __shfl_xor(vx, 16); vy += __shfl_xor(vy, 16);
        vx += __shfl_xor(vx, 32); vy += __shfl_xor(vy, 32);
        if (sub == 0) {
            float2 o = make_float2(0.5f * (vx + bx), 0.5f * (vy + by));
            *reinterpret_cast<float2*>(outp + (size_t)i * 16 + 2 * fp) = o;
        }
    }
}

extern "C" void kernel_launch(void* const* d_in, const int* in_sizes, int n_in,
                              void* d_out, int out_size, void* d_ws, size_t ws_size,
                              hipStream_t stream) {
    const float* x   = (const float*)d_in[0];
    const int*   eia = (const int*)d_in[1];
    const int*   eib = (const int*)d_in[2];
    const float* W1a = (const float*)d_in[3];
    const float* b1a = (const float*)d_in[4];
    const float* W1b = (const float*)d_in[5];
    const float* b1b = (const float*)d_in[6];
    const float* W2a = (const float*)d_in[7];
    const float* b2a = (const float*)d_in[8];
    const float* W2b = (const float*)d_in[9];
    const float* b2b = (const float*)d_in[10];
    float* out = (float*)d_out;

    const int n  = in_sizes[0] / 64;
    const int Ea = in_sizes[1] / 2;
    const int Eb = in_sizes[2] / 2;
    const int Et = Ea + Eb;
    const int n2 = 2 * n;

    int shift = 10;
    while ((((long long)n + (1LL << shift) - 1) >> shift) > 128) ++shift;
    const int nbuk = (int)(((long long)n + (1LL << shift) - 1) >> shift);
    const int nbuk2 = 2 * nbuk;
    const int Emaxrel = Ea > Eb ? Ea : Eb;
    int CAP = ((Emaxrel / (nbuk > 0 ? nbuk : 1)) * 3) / 2 + 2048;
    CAP = (CAP + 63) & ~63;

    char* wsp = (char*)d_ws;
    size_t off = 0;
    auto carve = [&](size_t elems) { void* p = wsp + off; off += ((elems + 3) & ~(size_t)3) * 4; return p; };
    float* dinv2    = (float*)carve(n2);
    int2*  rowse2   = (int2*)carve((size_t)n2 * 2);
    int*   bcursor2 = (int*)carve(MAXBUK);
    int*   col2     = (int*)carve((size_t)nbuk2 * CAP);
    ushort_t* ya    = (ushort_t*)carve((size_t)32 * n);   // 64n bf16
    ushort_t* yb    = (ushort_t*)carve((size_t)32 * n);
    ushort_t* za    = (ushort_t*)carve((size_t)8 * n);    // 16n bf16
    ushort_t* zb    = (ushort_t*)carve((size_t)8 * n);
    size_t pair_words = (size_t)nbuk2 * CAP;
    size_t big_words = pair_words > (size_t)32 * n ? pair_words : (size_t)32 * n;
    void*  big      = carve(big_words);
    uint_t* pairs   = (uint_t*)big;
    ushort_t* H     = (ushort_t*)big;

    const int T = 256;
    auto cdiv = [](long long a, long long b) { return (unsigned)((a + b - 1) / b); };

    // ---- combined CSR build (no pre-count pass) ----
    init_caps_kernel<<<1, 256, 0, stream>>>(bcursor2, nbuk2, CAP);
    bfill2_kernel<<<cdiv(Et, BF_CHUNK), T, 0, stream>>>(eia, eib, bcursor2, pairs,
                                                        Ea, Eb, Et, shift, nbuk, n);
    if (shift == 10)
        bucket_csr_kernel<1024><<<nbuk2, 1024, 0, stream>>>(pairs, bcursor2, rowse2, dinv2,
                                                            col2, nbuk, shift, n, CAP);
    else if (shift == 11)
        bucket_csr_kernel<2048><<<nbuk2, 1024, 0, stream>>>(pairs, bcursor2, rowse2, dinv2,
                                                            col2, nbuk, shift, n, CAP);
    else
        bucket_csr_kernel<4096><<<nbuk2, 1024, 0, stream>>>(pairs, bcursor2, rowse2, dinv2,
                                                            col2, nbuk, shift, n, CAP);

    const unsigned AGG_GRID = 2048;

    // ---- layer 1 ----
    gemm2_mfma_bf16_kernel<<<cdiv(n, 64), T, 0, stream>>>(x, W1a, W1b, dinv2, dinv2 + n, ya, yb, n);
    agg64_dual_kernel<<<AGG_GRID, T, 0, stream>>>(ya, yb, rowse2, col2, dinv2, b1a, b1b, H, n);

    // ---- layer 2 ----
    gemm2_mfma_h_kernel<<<cdiv(n, 64), T, 0, stream>>>(H, W2a, W2b, dinv2, dinv2 + n, za, zb, n);
    agg16_dual_kernel<<<AGG_GRID, T, 0, stream>>>(za, zb, rowse2, col2, dinv2, b2a, b2b, out, n);
}

// Round 14
// 157.054 us; speedup vs baseline: 1.5435x; 1.0712x over previous
//
#include <hip/hip_runtime.h>

#define XS_STRIDE 72
#define MAXBUK 256
#define BF_CHUNK 4096

typedef unsigned short ushort_t;
typedef unsigned int uint_t;
typedef __attribute__((ext_vector_type(8))) short short8_t;
typedef __attribute__((ext_vector_type(4))) float f32x4;

__device__ __forceinline__ ushort_t f2bf(float x) {
    uint_t u = __float_as_uint(x);
    uint_t r = (u + 0x7FFFu + ((u >> 16) & 1u)) >> 16;
    return (ushort_t)r;
}
__device__ __forceinline__ float bf2f(ushort_t h) {
    return __uint_as_float((uint_t)h << 16);
}
__device__ __forceinline__ float bf2f_lo(uint_t g) { return __uint_as_float(g << 16); }
__device__ __forceinline__ float bf2f_hi(uint_t g) { return __uint_as_float(g & 0xFFFF0000u); }

// bcursor2[i] = i*CAP (fixed-capacity bucket bases)
__global__ void init_caps_kernel(int* bcursor2, int nbuk2, int CAP) {
    int i = blockIdx.x * blockDim.x + threadIdx.x;
    if (i < nbuk2) bcursor2[i] = i * CAP;
}

// Bin packed (src<<shift | dst_local) by combined bucket id; direct reservation
// into fixed-capacity buckets (no pre-count pass).
__global__ void bfill2_kernel(const int* __restrict__ eia, const int* __restrict__ eib,
                              int* __restrict__ bcursor, uint_t* __restrict__ pairs,
                              int Ea, int Eb, int Et, int shift, int nbuk, int n) {
    __shared__ int cnt[MAXBUK];
    __shared__ int base[MAXBUK];
    __shared__ int off[MAXBUK];
    const int t = threadIdx.x;
    const long long e0 = (long long)blockIdx.x * BF_CHUNK;
    const int nedge = (int)min((long long)BF_CHUNK, (long long)Et - e0);
    const int nbuk2 = 2 * nbuk;
    const uint_t mask = (1u << shift) - 1u;
    for (int i = t; i < nbuk2; i += 256) cnt[i] = 0;
    __syncthreads();
    for (int i = t; i < nedge; i += 256) {
        long long e = e0 + i;
        int rel = (e >= Ea);
        int d = rel ? eib[Eb + (e - Ea)] : eia[Ea + e];
        atomicAdd(&cnt[(rel ? nbuk : 0) + (d >> shift)], 1);
    }
    __syncthreads();
    for (int i = t; i < nbuk2; i += 256) {
        off[i] = 0;
        base[i] = cnt[i] ? atomicAdd(&bcursor[i], cnt[i]) : 0;
    }
    __syncthreads();
    for (int i = t; i < nedge; i += 256) {
        long long e = e0 + i;
        int rel = (e >= Ea);
        int s, d;
        if (rel) { s = eib[e - Ea]; d = eib[Eb + (e - Ea)]; }
        else     { s = eia[e];      d = eia[Ea + e]; }
        int b = (rel ? nbuk : 0) + (d >> shift);
        int p = base[b] + atomicAdd(&off[b], 1);
        pairs[p] = ((uint_t)s << shift) | ((uint_t)d & mask);
    }
}

// Per-bucket CSR build from packed pairs in fixed-capacity buckets.
// Writes interleaved rowse (int[4n]: a.s,a.e,b.s,b.e) and dinv (float[2n]: da,db).
template<int NPB>
__global__ void bucket_csr_kernel(const uint_t* __restrict__ pairs,
                                  const int* __restrict__ bcursor2,
                                  int* __restrict__ rowse, float* __restrict__ dinv,
                                  int* __restrict__ col2,
                                  int nbuk, int shift, int n, int CAP) {
    constexpr int BLK = 1024;
    constexpr int K = NPB / BLK;
    constexpr uint_t MASK = NPB - 1;
    __shared__ int cnt[NPB];
    __shared__ int wsum[16];
    const int b = blockIdx.x;
    const int t = threadIdx.x;
    const int lane = t & 63;
    const int w = t >> 6;
    const int rel = (b >= nbuk);
    const int blocal = rel ? b - nbuk : b;
    const int nodelo = blocal << shift;
    const int NN = min(NPB, n - nodelo);
    const int p0 = b * CAP;
    const int p1 = bcursor2[b];

    #pragma unroll
    for (int k = 0; k < K; ++k) cnt[t + k * BLK] = 0;
    __syncthreads();
    for (int idx = p0 + t; idx < p1; idx += BLK)
        atomicAdd(&cnt[pairs[idx] & MASK], 1);
    __syncthreads();

    int a[K]; int s = 0;
    #pragma unroll
    for (int k = 0; k < K; ++k) { a[k] = cnt[t * K + k]; s += a[k]; }
    int sc = s;
    #pragma unroll
    for (int d = 1; d < 64; d <<= 1) {
        int u = __shfl_up(sc, d);
        if (lane >= d) sc += u;
    }
    if (lane == 63) wsum[w] = sc;
    __syncthreads();
    if (t < 16) {
        int v = wsum[t];
        int scc = v;
        #pragma unroll
        for (int d = 1; d < 16; d <<= 1) {
            int u = __shfl_up(scc, d);
            if (t >= d) scc += u;
        }
        wsum[t] = scc - v;
    }
    __syncthreads();
    int run = p0 + wsum[w] + sc - s;
    __syncthreads();
    #pragma unroll
    for (int k = 0; k < K; ++k) {
        int j = t * K + k;
        cnt[j] = run;
        if (j < NN) {
            int node = nodelo + j;
            *reinterpret_cast<int2*>(rowse + 4 * (size_t)node + (rel ? 2 : 0)) =
                make_int2(run, run + a[k]);
            dinv[2 * (size_t)node + rel] = rsqrtf((float)(a[k] + 1));
        }
        run += a[k];
    }
    __syncthreads();
    for (int idx = p0 + t; idx < p1; idx += BLK) {
        uint_t p = pairs[idx];
        int pos = atomicAdd(&cnt[p & MASK], 1);
        col2[pos] = (int)(p >> shift);
    }
}

// ---- MFMA dual-weight GEMM (layer 1): ya|yb = (Xbf16 @ [Wa|Wb]) * dinv, bf16 out ----
__global__ void gemm2_mfma_bf16_kernel(const float* __restrict__ X,
                                       const float* __restrict__ Wa, const float* __restrict__ Wb,
                                       const float2* __restrict__ dinv,
                                       ushort_t* __restrict__ ya, ushort_t* __restrict__ yb, int n) {
    __shared__ ushort_t Xs[64 * XS_STRIDE];
    __shared__ ushort_t Wt[128 * XS_STRIDE];
    const int tid = threadIdx.x;
    const int rowbase = blockIdx.x * 64;

    {
        int row = tid >> 2, cg = tid & 3;
        int grow = rowbase + row;
        float4 v[4];
        if (grow < n) {
            const float4* xr = reinterpret_cast<const float4*>(X + (size_t)grow * 64 + cg * 16);
            v[0] = xr[0]; v[1] = xr[1]; v[2] = xr[2]; v[3] = xr[3];
        } else {
            v[0] = v[1] = v[2] = v[3] = make_float4(0.f, 0.f, 0.f, 0.f);
        }
        ushort_t* dst = &Xs[row * XS_STRIDE + cg * 16];
        #pragma unroll
        for (int q = 0; q < 4; ++q) {
            dst[q * 4 + 0] = f2bf(v[q].x); dst[q * 4 + 1] = f2bf(v[q].y);
            dst[q * 4 + 2] = f2bf(v[q].z); dst[q * 4 + 3] = f2bf(v[q].w);
        }
    }
    for (int idx = tid; idx < 4096; idx += 256) {
        int k = idx >> 6, c = idx & 63;
        Wt[c * XS_STRIDE + k] = f2bf(Wa[idx]);
        Wt[(64 + c) * XS_STRIDE + k] = f2bf(Wb[idx]);
    }
    __syncthreads();

    const int wid = tid >> 6, lane = tid & 63;
    const int lrow = lane & 15;
    const int lk = (lane >> 4) * 8;

    short8_t a0 = *reinterpret_cast<const short8_t*>(&Xs[(wid * 16 + lrow) * XS_STRIDE + lk]);
    short8_t a1 = *reinterpret_cast<const short8_t*>(&Xs[(wid * 16 + lrow) * XS_STRIDE + 32 + lk]);

    f32x4 acc[8];
    #pragma unroll
    for (int ct = 0; ct < 8; ++ct) {
        short8_t b0 = *reinterpret_cast<const short8_t*>(&Wt[(ct * 16 + lrow) * XS_STRIDE + lk]);
        short8_t b1 = *reinterpret_cast<const short8_t*>(&Wt[(ct * 16 + lrow) * XS_STRIDE + 32 + lk]);
        f32x4 c = {0.f, 0.f, 0.f, 0.f};
        c = __builtin_amdgcn_mfma_f32_16x16x32_bf16(a0, b0, c, 0, 0, 0);
        c = __builtin_amdgcn_mfma_f32_16x16x32_bf16(a1, b1, c, 0, 0, 0);
        acc[ct] = c;
    }

    const int rq = (lane >> 4) * 4;
    #pragma unroll
    for (int r = 0; r < 4; ++r) {
        int grow = rowbase + wid * 16 + rq + r;
        if (grow < n) {
            float2 dv = dinv[grow];
            #pragma unroll
            for (int ct = 0; ct < 8; ++ct) {
                int col = ct * 16 + lrow;
                float v = acc[ct][r];
                if (col < 64) ya[(size_t)grow * 64 + col] = f2bf(v * dv.x);
                else          yb[(size_t)grow * 64 + (col - 64)] = f2bf(v * dv.y);
            }
        }
    }
}

// ---- MFMA layer-2 GEMM: za|zb = (Hbf16 @ [W2a|W2b]) * dinv, bf16 out ----
__global__ void gemm2_mfma_h_kernel(const ushort_t* __restrict__ H,
                                    const float* __restrict__ W2a, const float* __restrict__ W2b,
                                    const float2* __restrict__ dinv,
                                    ushort_t* __restrict__ za, ushort_t* __restrict__ zb, int n) {
    __shared__ ushort_t Hs[64 * XS_STRIDE];
    __shared__ ushort_t Wt[32 * XS_STRIDE];
    const int tid = threadIdx.x;
    const int rowbase = blockIdx.x * 64;

    {
        int row = tid >> 2, cg = tid & 3;
        int grow = rowbase + row;
        uint4 v0 = {0, 0, 0, 0}, v1 = {0, 0, 0, 0};
        if (grow < n) {
            const uint4* hr = reinterpret_cast<const uint4*>(H + (size_t)grow * 64 + cg * 16);
            v0 = hr[0]; v1 = hr[1];
        }
        uint4* dst = reinterpret_cast<uint4*>(&Hs[row * XS_STRIDE + cg * 16]);
        dst[0] = v0; dst[1] = v1;
    }
    for (int idx = tid; idx < 2048; idx += 256) {
        int c = idx & 31, k = idx >> 5;
        float v = (c < 16) ? W2a[k * 16 + c] : W2b[k * 16 + (c - 16)];
        Wt[c * XS_STRIDE + k] = f2bf(v);
    }
    __syncthreads();

    const int wid = tid >> 6, lane = tid & 63;
    const int lrow = lane & 15;
    const int lk = (lane >> 4) * 8;
    const int rq = (lane >> 4) * 4;

    short8_t a0 = *reinterpret_cast<const short8_t*>(&Hs[(wid * 16 + lrow) * XS_STRIDE + lk]);
    short8_t a1 = *reinterpret_cast<const short8_t*>(&Hs[(wid * 16 + lrow) * XS_STRIDE + 32 + lk]);

    f32x4 c0 = {0.f, 0.f, 0.f, 0.f}, c1 = {0.f, 0.f, 0.f, 0.f};
    {
        short8_t b0 = *reinterpret_cast<const short8_t*>(&Wt[lrow * XS_STRIDE + lk]);
        short8_t b1 = *reinterpret_cast<const short8_t*>(&Wt[lrow * XS_STRIDE + 32 + lk]);
        c0 = __builtin_amdgcn_mfma_f32_16x16x32_bf16(a0, b0, c0, 0, 0, 0);
        c0 = __builtin_amdgcn_mfma_f32_16x16x32_bf16(a1, b1, c0, 0, 0, 0);
    }
    {
        short8_t b0 = *reinterpret_cast<const short8_t*>(&Wt[(16 + lrow) * XS_STRIDE + lk]);
        short8_t b1 = *reinterpret_cast<const short8_t*>(&Wt[(16 + lrow) * XS_STRIDE + 32 + lk]);
        c1 = __builtin_amdgcn_mfma_f32_16x16x32_bf16(a0, b0, c1, 0, 0, 0);
        c1 = __builtin_amdgcn_mfma_f32_16x16x32_bf16(a1, b1, c1, 0, 0, 0);
    }
    #pragma unroll
    for (int r = 0; r < 4; ++r) {
        int node = rowbase + wid * 16 + rq + r;
        if (node < n) {
            float2 dv = dinv[node];
            za[(size_t)node * 16 + lrow] = f2bf(c0[r] * dv.x);
            zb[(size_t)node * 16 + lrow] = f2bf(c1[r] * dv.y);
        }
    }
}

// ---- fused dual-relation aggregation, layer 1 (bf16, F=64), h out bf16 ----
// uint2 gather lanes: lane = (quarter 0..3, feature-quad 0..15); 1 VMEM instr = 4 edges.
__global__ void __launch_bounds__(256, 8)
agg64_dual_kernel(const ushort_t* __restrict__ ya, const ushort_t* __restrict__ yb,
                  const int4* __restrict__ rowse4, const int* __restrict__ col2,
                  const float2* __restrict__ dinv,
                  const float* __restrict__ ba, const float* __restrict__ bb,
                  ushort_t* __restrict__ h, int n) {
    const int lane = threadIdx.x & 63;
    const int quarter = lane >> 4;
    const int fp = lane & 15;            // feats 4fp..4fp+3
    const int gw = (blockIdx.x * blockDim.x + threadIdx.x) >> 6;
    const int nw = (gridDim.x * blockDim.x) >> 6;
    const float bi0 = ba[4 * fp] + bb[4 * fp];
    const float bi1 = ba[4 * fp + 1] + bb[4 * fp + 1];
    const float bi2 = ba[4 * fp + 2] + bb[4 * fp + 2];
    const float bi3 = ba[4 * fp + 3] + bb[4 * fp + 3];
    for (int i = gw; i < n; i += nw) {
        const int4 se = rowse4[i];
        const float2 dv = dinv[i];
        float a0 = 0.f, a1 = 0.f, a2 = 0.f, a3 = 0.f;
        float c0 = 0.f, c1 = 0.f, c2 = 0.f, c3 = 0.f;
        if (quarter == 0) {
            uint2 g = *reinterpret_cast<const uint2*>(ya + (size_t)i * 64 + 4 * fp);
            a0 = bf2f_lo(g.x); a1 = bf2f_hi(g.x); a2 = bf2f_lo(g.y); a3 = bf2f_hi(g.y);
            uint2 gb = *reinterpret_cast<const uint2*>(yb + (size_t)i * 64 + 4 * fp);
            c0 = bf2f_lo(gb.x); c1 = bf2f_hi(gb.x); c2 = bf2f_lo(gb.y); c3 = bf2f_hi(gb.y);
        }
        // relation a
        for (int base0 = se.x; base0 < se.y; base0 += 64) {
            const int m = min(64, se.y - base0);
            int cv = (lane < m) ? col2[base0 + lane] : 0;
            int j = 0;
            for (; j + 8 <= m; j += 8) {
                int e0 = __shfl(cv, j + quarter);
                int e1 = __shfl(cv, j + 4 + quarter);
                uint2 g0 = *reinterpret_cast<const uint2*>(ya + (size_t)e0 * 64 + 4 * fp);
                uint2 g1 = *reinterpret_cast<const uint2*>(ya + (size_t)e1 * 64 + 4 * fp);
                a0 += bf2f_lo(g0.x) + bf2f_lo(g1.x);
                a1 += bf2f_hi(g0.x) + bf2f_hi(g1.x);
                a2 += bf2f_lo(g0.y) + bf2f_lo(g1.y);
                a3 += bf2f_hi(g0.y) + bf2f_hi(g1.y);
            }
            if (j < m) {
                int i0 = j + quarter, i1 = j + 4 + quarter;
                int e0 = __shfl(cv, i0 & 63);
                int e1 = __shfl(cv, i1 & 63);
                if (i0 < m) {
                    uint2 g = *reinterpret_cast<const uint2*>(ya + (size_t)e0 * 64 + 4 * fp);
                    a0 += bf2f_lo(g.x); a1 += bf2f_hi(g.x);
                    a2 += bf2f_lo(g.y); a3 += bf2f_hi(g.y);
                }
                if (i1 < m) {
                    uint2 g = *reinterpret_cast<const uint2*>(ya + (size_t)e1 * 64 + 4 * fp);
                    a0 += bf2f_lo(g.x); a1 += bf2f_hi(g.x);
                    a2 += bf2f_lo(g.y); a3 += bf2f_hi(g.y);
                }
            }
        }
        // relation b
        for (int base0 = se.z; base0 < se.w; base0 += 64) {
            const int m = min(64, se.w - base0);
            int cv = (lane < m) ? col2[base0 + lane] : 0;
            int j = 0;
            for (; j + 8 <= m; j += 8) {
                int e0 = __shfl(cv, j + quarter);
                int e1 = __shfl(cv, j + 4 + quarter);
                uint2 g0 = *reinterpret_cast<const uint2*>(yb + (size_t)e0 * 64 + 4 * fp);
                uint2 g1 = *reinterpret_cast<const uint2*>(yb + (size_t)e1 * 64 + 4 * fp);
                c0 += bf2f_lo(g0.x) + bf2f_lo(g1.x);
                c1 += bf2f_hi(g0.x) + bf2f_hi(g1.x);
                c2 += bf2f_lo(g0.y) + bf2f_lo(g1.y);
                c3 += bf2f_hi(g0.y) + bf2f_hi(g1.y);
            }
            if (j < m) {
                int i0 = j + quarter, i1 = j + 4 + quarter;
                int e0 = __shfl(cv, i0 & 63);
                int e1 = __shfl(cv, i1 & 63);
                if (i0 < m) {
                    uint2 g = *reinterpret_cast<const uint2*>(yb + (size_t)e0 * 64 + 4 * fp);
                    c0 += bf2f_lo(g.x); c1 += bf2f_hi(g.x);
                    c2 += bf2f_lo(g.y); c3 += bf2f_hi(g.y);
                }
                if (i1 < m) {
                    uint2 g = *reinterpret_cast<const uint2*>(yb + (size_t)e1 * 64 + 4 * fp);
                    c0 += bf2f_lo(g.x); c1 += bf2f_hi(g.x);
                    c2 += bf2f_lo(g.y); c3 += bf2f_hi(g.y);
                }
            }
        }
        // combine with dinv per-lane, then reduce over quarters
        float v0 = a0 * dv.x + c0 * dv.y;
        float v1 = a1 * dv.x + c1 * dv.y;
        float v2 = a2 * dv.x + c2 * dv.y;
        float v3 = a3 * dv.x + c3 * dv.y;
        v0 += __shfl_xor(v0, 16); v1 += __shfl_xor(v1, 16);
        v2 += __shfl_xor(v2, 16); v3 += __shfl_xor(v3, 16);
        v0 += __shfl_xor(v0, 32); v1 += __shfl_xor(v1, 32);
        v2 += __shfl_xor(v2, 32); v3 += __shfl_xor(v3, 32);
        if (quarter == 0) {
            float r0 = fmaxf(0.5f * (v0 + bi0), 0.0f);
            float r1 = fmaxf(0.5f * (v1 + bi1), 0.0f);
            float r2 = fmaxf(0.5f * (v2 + bi2), 0.0f);
            float r3 = fmaxf(0.5f * (v3 + bi3), 0.0f);
            uint2 p;
            p.x = (uint_t)f2bf(r0) | ((uint_t)f2bf(r1) << 16);
            p.y = (uint_t)f2bf(r2) | ((uint_t)f2bf(r3) << 16);
            *reinterpret_cast<uint2*>(h + (size_t)i * 64 + 4 * fp) = p;
        }
    }
}

// ---- fused dual-relation aggregation, layer 2 (bf16, F=16) ----
// lane = (8 edge-slots, 8 feat-pairs); one instruction = 8 edges.
__global__ void __launch_bounds__(256, 8)
agg16_dual_kernel(const ushort_t* __restrict__ za, const ushort_t* __restrict__ zb,
                  const int4* __restrict__ rowse4, const int* __restrict__ col2,
                  const float2* __restrict__ dinv,
                  const float* __restrict__ ba, const float* __restrict__ bb,
                  float* __restrict__ outp, int n) {
    const int lane = threadIdx.x & 63;
    const int fp   = lane & 7;        // feats 2fp, 2fp+1
    const int sub  = lane >> 3;       // 0..7 edge slots
    const int gw   = (blockIdx.x * blockDim.x + threadIdx.x) >> 6;
    const int nw   = (gridDim.x * blockDim.x) >> 6;
    const float bx = ba[2 * fp] + bb[2 * fp];
    const float by = ba[2 * fp + 1] + bb[2 * fp + 1];
    for (int i = gw; i < n; i += nw) {
        const int4 se = rowse4[i];
        const float2 dv = dinv[i];
        int ea = se.x + sub, eb = se.z + sub;
        const int e1a = se.y, e1b = se.w;
        float ax = 0.f, ay = 0.f, bx2 = 0.f, by2 = 0.f;
        if (sub == 0) {
            uint_t ga = *reinterpret_cast<const uint_t*>(za + (size_t)i * 16 + 2 * fp);
            uint_t gb = *reinterpret_cast<const uint_t*>(zb + (size_t)i * 16 + 2 * fp);
            ax = bf2f_lo(ga); ay = bf2f_hi(ga);
            bx2 = bf2f_lo(gb); by2 = bf2f_hi(gb);
        }
        for (; ea + 8 < e1a && eb + 8 < e1b; ea += 16, eb += 16) {
            int c0 = col2[ea], c1 = col2[ea + 8];
            int d0 = col2[eb], d1 = col2[eb + 8];
            uint_t g0 = *reinterpret_cast<const uint_t*>(za + (size_t)c0 * 16 + 2 * fp);
            uint_t g1 = *reinterpret_cast<const uint_t*>(za + (size_t)c1 * 16 + 2 * fp);
            uint_t g2 = *reinterpret_cast<const uint_t*>(zb + (size_t)d0 * 16 + 2 * fp);
            uint_t g3 = *reinterpret_cast<const uint_t*>(zb + (size_t)d1 * 16 + 2 * fp);
            ax += bf2f_lo(g0) + bf2f_lo(g1);  ay += bf2f_hi(g0) + bf2f_hi(g1);
            bx2 += bf2f_lo(g2) + bf2f_lo(g3); by2 += bf2f_hi(g2) + bf2f_hi(g3);
        }
        for (; ea < e1a; ea += 8) {
            uint_t g = *reinterpret_cast<const uint_t*>(za + (size_t)col2[ea] * 16 + 2 * fp);
            ax += bf2f_lo(g); ay += bf2f_hi(g);
        }
        for (; eb < e1b; eb += 8) {
            uint_t g = *reinterpret_cast<const uint_t*>(zb + (size_t)col2[eb] * 16 + 2 * fp);
            bx2 += bf2f_lo(g); by2 += bf2f_hi(g);
        }
        float vx = ax * dv.x + bx2 * dv.y;
        float vy = ay * dv.x + by2 * dv.y;
        vx += __shfl_xor(vx, 8);  vy += __shfl_xor(vy, 8);
        vx += __shfl_xor(vx, 16); vy += __shfl_xor(vy, 16);
        vx += __shfl_xor(vx, 32); vy += __shfl_xor(vy, 32);
        if (sub == 0) {
            float2 o = make_float2(0.5f * (vx + bx), 0.5f * (vy + by));
            *reinterpret_cast<float2*>(outp + (size_t)i * 16 + 2 * fp) = o;
        }
    }
}

extern "C" void kernel_launch(void* const* d_in, const int* in_sizes, int n_in,
                              void* d_out, int out_size, void* d_ws, size_t ws_size,
                              hipStream_t stream) {
    const float* x   = (const float*)d_in[0];
    const int*   eia = (const int*)d_in[1];
    const int*   eib = (const int*)d_in[2];
    const float* W1a = (const float*)d_in[3];
    const float* b1a = (const float*)d_in[4];
    const float* W1b = (const float*)d_in[5];
    const float* b1b = (const float*)d_in[6];
    const float* W2a = (const float*)d_in[7];
    const float* b2a = (const float*)d_in[8];
    const float* W2b = (const float*)d_in[9];
    const float* b2b = (const float*)d_in[10];
    float* out = (float*)d_out;

    const int n  = in_sizes[0] / 64;
    const int Ea = in_sizes[1] / 2;
    const int Eb = in_sizes[2] / 2;
    const int Et = Ea + Eb;
    const int n2 = 2 * n;

    int shift = 10;
    while ((((long long)n + (1LL << shift) - 1) >> shift) > 128) ++shift;
    const int nbuk = (int)(((long long)n + (1LL << shift) - 1) >> shift);
    const int nbuk2 = 2 * nbuk;
    const int Emaxrel = Ea > Eb ? Ea : Eb;
    int CAP = ((Emaxrel / (nbuk > 0 ? nbuk : 1)) * 3) / 2 + 2048;
    CAP = (CAP + 63) & ~63;

    char* wsp = (char*)d_ws;
    size_t off = 0;
    auto carve = [&](size_t elems) { void* p = wsp + off; off += ((elems + 3) & ~(size_t)3) * 4; return p; };
    float* dinv     = (float*)carve(n2);               // [n][2] interleaved
    int*   rowse    = (int*)carve((size_t)n * 4);      // [n][4] interleaved
    int*   bcursor2 = (int*)carve(MAXBUK);
    int*   col2     = (int*)carve((size_t)nbuk2 * CAP);
    ushort_t* ya    = (ushort_t*)carve((size_t)32 * n);   // 64n bf16
    ushort_t* yb    = (ushort_t*)carve((size_t)32 * n);
    ushort_t* za    = (ushort_t*)carve((size_t)8 * n);    // 16n bf16
    ushort_t* zb    = (ushort_t*)carve((size_t)8 * n);
    size_t pair_words = (size_t)nbuk2 * CAP;
    size_t big_words = pair_words > (size_t)32 * n ? pair_words : (size_t)32 * n;
    void*  big      = carve(big_words);
    uint_t* pairs   = (uint_t*)big;
    ushort_t* H     = (ushort_t*)big;

    const int T = 256;
    auto cdiv = [](long long a, long long b) { return (unsigned)((a + b - 1) / b); };

    // ---- combined CSR build (no pre-count pass) ----
    init_caps_kernel<<<1, 256, 0, stream>>>(bcursor2, nbuk2, CAP);
    bfill2_kernel<<<cdiv(Et, BF_CHUNK), T, 0, stream>>>(eia, eib, bcursor2, pairs,
                                                        Ea, Eb, Et, shift, nbuk, n);
    if (shift == 10)
        bucket_csr_kernel<1024><<<nbuk2, 1024, 0, stream>>>(pairs, bcursor2, rowse, dinv,
                                                            col2, nbuk, shift, n, CAP);
    else if (shift == 11)
        bucket_csr_kernel<2048><<<nbuk2, 1024, 0, stream>>>(pairs, bcursor2, rowse, dinv,
                                                            col2, nbuk, shift, n, CAP);
    else
        bucket_csr_kernel<4096><<<nbuk2, 1024, 0, stream>>>(pairs, bcursor2, rowse, dinv,
                                                            col2, nbuk, shift, n, CAP);

    const unsigned AGG_GRID = 2048;

    // ---- layer 1 ----
    gemm2_mfma_bf16_kernel<<<cdiv(n, 64), T, 0, stream>>>(x, W1a, W1b, (const float2*)dinv, ya, yb, n);
    agg64_dual_kernel<<<AGG_GRID, T, 0, stream>>>(ya, yb, (const int4*)rowse, col2,
                                                  (const float2*)dinv, b1a, b1b, H, n);

    // ---- layer 2 ----
    gemm2_mfma_h_kernel<<<cdiv(n, 64), T, 0, stream>>>(H, W2a, W2b, (const float2*)dinv, za, zb, n);
    agg16_dual_kernel<<<AGG_GRID, T, 0, stream>>>(za, zb, (const int4*)rowse, col2,
                                                  (const float2*)dinv, b2a, b2b, out, n);
}

// Round 15
// 154.527 us; speedup vs baseline: 1.5687x; 1.0164x over previous
//
#include <hip/hip_runtime.h>

#define XS_STRIDE 72
#define MAXBUK 256
#define BF_CHUNK 4096

typedef unsigned short ushort_t;
typedef unsigned int uint_t;
typedef __attribute__((ext_vector_type(8))) short short8_t;
typedef __attribute__((ext_vector_type(4))) float f32x4;

__device__ __forceinline__ ushort_t f2bf(float x) {
    uint_t u = __float_as_uint(x);
    uint_t r = (u + 0x7FFFu + ((u >> 16) & 1u)) >> 16;
    return (ushort_t)r;
}
__device__ __forceinline__ float bf2f(ushort_t h) {
    return __uint_as_float((uint_t)h << 16);
}
__device__ __forceinline__ float bf2f_lo(uint_t g) { return __uint_as_float(g << 16); }
__device__ __forceinline__ float bf2f_hi(uint_t g) { return __uint_as_float(g & 0xFFFF0000u); }

// bcursor2[i] = i*CAP (fixed-capacity bucket bases)
__global__ void init_caps_kernel(int* bcursor2, int nbuk2, int CAP) {
    int i = blockIdx.x * blockDim.x + threadIdx.x;
    if (i < nbuk2) bcursor2[i] = i * CAP;
}

// Bin packed (src<<shift | dst_local) by combined bucket id; direct reservation
// into fixed-capacity buckets (no pre-count pass).
__global__ void bfill2_kernel(const int* __restrict__ eia, const int* __restrict__ eib,
                              int* __restrict__ bcursor, uint_t* __restrict__ pairs,
                              int Ea, int Eb, int Et, int shift, int nbuk, int n) {
    __shared__ int cnt[MAXBUK];
    __shared__ int base[MAXBUK];
    __shared__ int off[MAXBUK];
    const int t = threadIdx.x;
    const long long e0 = (long long)blockIdx.x * BF_CHUNK;
    const int nedge = (int)min((long long)BF_CHUNK, (long long)Et - e0);
    const int nbuk2 = 2 * nbuk;
    const uint_t mask = (1u << shift) - 1u;
    for (int i = t; i < nbuk2; i += 256) cnt[i] = 0;
    __syncthreads();
    for (int i = t; i < nedge; i += 256) {
        long long e = e0 + i;
        int rel = (e >= Ea);
        int d = rel ? eib[Eb + (e - Ea)] : eia[Ea + e];
        atomicAdd(&cnt[(rel ? nbuk : 0) + (d >> shift)], 1);
    }
    __syncthreads();
    for (int i = t; i < nbuk2; i += 256) {
        off[i] = 0;
        base[i] = cnt[i] ? atomicAdd(&bcursor[i], cnt[i]) : 0;
    }
    __syncthreads();
    for (int i = t; i < nedge; i += 256) {
        long long e = e0 + i;
        int rel = (e >= Ea);
        int s, d;
        if (rel) { s = eib[e - Ea]; d = eib[Eb + (e - Ea)]; }
        else     { s = eia[e];      d = eia[Ea + e]; }
        int b = (rel ? nbuk : 0) + (d >> shift);
        int p = base[b] + atomicAdd(&off[b], 1);
        pairs[p] = ((uint_t)s << shift) | ((uint_t)d & mask);
    }
}

// Per-bucket CSR build from packed pairs in fixed-capacity buckets.
// Writes interleaved rowse (int[4n]: a.s,a.e,b.s,b.e) and dinv (float[2n]: da,db).
template<int NPB>
__global__ void bucket_csr_kernel(const uint_t* __restrict__ pairs,
                                  const int* __restrict__ bcursor2,
                                  int* __restrict__ rowse, float* __restrict__ dinv,
                                  int* __restrict__ col2,
                                  int nbuk, int shift, int n, int CAP) {
    constexpr int BLK = 1024;
    constexpr int K = NPB / BLK;
    constexpr uint_t MASK = NPB - 1;
    __shared__ int cnt[NPB];
    __shared__ int wsum[16];
    const int b = blockIdx.x;
    const int t = threadIdx.x;
    const int lane = t & 63;
    const int w = t >> 6;
    const int rel = (b >= nbuk);
    const int blocal = rel ? b - nbuk : b;
    const int nodelo = blocal << shift;
    const int NN = min(NPB, n - nodelo);
    const int p0 = b * CAP;
    const int p1 = bcursor2[b];

    #pragma unroll
    for (int k = 0; k < K; ++k) cnt[t + k * BLK] = 0;
    __syncthreads();
    for (int idx = p0 + t; idx < p1; idx += BLK)
        atomicAdd(&cnt[pairs[idx] & MASK], 1);
    __syncthreads();

    int a[K]; int s = 0;
    #pragma unroll
    for (int k = 0; k < K; ++k) { a[k] = cnt[t * K + k]; s += a[k]; }
    int sc = s;
    #pragma unroll
    for (int d = 1; d < 64; d <<= 1) {
        int u = __shfl_up(sc, d);
        if (lane >= d) sc += u;
    }
    if (lane == 63) wsum[w] = sc;
    __syncthreads();
    if (t < 16) {
        int v = wsum[t];
        int scc = v;
        #pragma unroll
        for (int d = 1; d < 16; d <<= 1) {
            int u = __shfl_up(scc, d);
            if (t >= d) scc += u;
        }
        wsum[t] = scc - v;
    }
    __syncthreads();
    int run = p0 + wsum[w] + sc - s;
    __syncthreads();
    #pragma unroll
    for (int k = 0; k < K; ++k) {
        int j = t * K + k;
        cnt[j] = run;
        if (j < NN) {
            int node = nodelo + j;
            *reinterpret_cast<int2*>(rowse + 4 * (size_t)node + (rel ? 2 : 0)) =
                make_int2(run, run + a[k]);
            dinv[2 * (size_t)node + rel] = rsqrtf((float)(a[k] + 1));
        }
        run += a[k];
    }
    __syncthreads();
    for (int idx = p0 + t; idx < p1; idx += BLK) {
        uint_t p = pairs[idx];
        int pos = atomicAdd(&cnt[p & MASK], 1);
        col2[pos] = (int)(p >> shift);
    }
}

// ---- MFMA dual-weight GEMM (layer 1): ya|yb = (Xbf16 @ [Wa|Wb]) * dinv, bf16 out ----
__global__ void gemm2_mfma_bf16_kernel(const float* __restrict__ X,
                                       const float* __restrict__ Wa, const float* __restrict__ Wb,
                                       const float2* __restrict__ dinv,
                                       ushort_t* __restrict__ ya, ushort_t* __restrict__ yb, int n) {
    __shared__ ushort_t Xs[64 * XS_STRIDE];
    __shared__ ushort_t Wt[128 * XS_STRIDE];
    const int tid = threadIdx.x;
    const int rowbase = blockIdx.x * 64;

    {
        int row = tid >> 2, cg = tid & 3;
        int grow = rowbase + row;
        float4 v[4];
        if (grow < n) {
            const float4* xr = reinterpret_cast<const float4*>(X + (size_t)grow * 64 + cg * 16);
            v[0] = xr[0]; v[1] = xr[1]; v[2] = xr[2]; v[3] = xr[3];
        } else {
            v[0] = v[1] = v[2] = v[3] = make_float4(0.f, 0.f, 0.f, 0.f);
        }
        ushort_t* dst = &Xs[row * XS_STRIDE + cg * 16];
        #pragma unroll
        for (int q = 0; q < 4; ++q) {
            dst[q * 4 + 0] = f2bf(v[q].x); dst[q * 4 + 1] = f2bf(v[q].y);
            dst[q * 4 + 2] = f2bf(v[q].z); dst[q * 4 + 3] = f2bf(v[q].w);
        }
    }
    for (int idx = tid; idx < 4096; idx += 256) {
        int k = idx >> 6, c = idx & 63;
        Wt[c * XS_STRIDE + k] = f2bf(Wa[idx]);
        Wt[(64 + c) * XS_STRIDE + k] = f2bf(Wb[idx]);
    }
    __syncthreads();

    const int wid = tid >> 6, lane = tid & 63;
    const int lrow = lane & 15;
    const int lk = (lane >> 4) * 8;

    short8_t a0 = *reinterpret_cast<const short8_t*>(&Xs[(wid * 16 + lrow) * XS_STRIDE + lk]);
    short8_t a1 = *reinterpret_cast<const short8_t*>(&Xs[(wid * 16 + lrow) * XS_STRIDE + 32 + lk]);

    f32x4 acc[8];
    #pragma unroll
    for (int ct = 0; ct < 8; ++ct) {
        short8_t b0 = *reinterpret_cast<const short8_t*>(&Wt[(ct * 16 + lrow) * XS_STRIDE + lk]);
        short8_t b1 = *reinterpret_cast<const short8_t*>(&Wt[(ct * 16 + lrow) * XS_STRIDE + 32 + lk]);
        f32x4 c = {0.f, 0.f, 0.f, 0.f};
        c = __builtin_amdgcn_mfma_f32_16x16x32_bf16(a0, b0, c, 0, 0, 0);
        c = __builtin_amdgcn_mfma_f32_16x16x32_bf16(a1, b1, c, 0, 0, 0);
        acc[ct] = c;
    }

    const int rq = (lane >> 4) * 4;
    #pragma unroll
    for (int r = 0; r < 4; ++r) {
        int grow = rowbase + wid * 16 + rq + r;
        if (grow < n) {
            float2 dv = dinv[grow];
            #pragma unroll
            for (int ct = 0; ct < 8; ++ct) {
                int col = ct * 16 + lrow;
                float v = acc[ct][r];
                if (col < 64) ya[(size_t)grow * 64 + col] = f2bf(v * dv.x);
                else          yb[(size_t)grow * 64 + (col - 64)] = f2bf(v * dv.y);
            }
        }
    }
}

// ---- MFMA layer-2 GEMM: za|zb = (Hbf16 @ [W2a|W2b]) * dinv, bf16 out ----
__global__ void gemm2_mfma_h_kernel(const ushort_t* __restrict__ H,
                                    const float* __restrict__ W2a, const float* __restrict__ W2b,
                                    const float2* __restrict__ dinv,
                                    ushort_t* __restrict__ za, ushort_t* __restrict__ zb, int n) {
    __shared__ ushort_t Hs[64 * XS_STRIDE];
    __shared__ ushort_t Wt[32 * XS_STRIDE];
    const int tid = threadIdx.x;
    const int rowbase = blockIdx.x * 64;

    {
        int row = tid >> 2, cg = tid & 3;
        int grow = rowbase + row;
        uint4 v0 = {0, 0, 0, 0}, v1 = {0, 0, 0, 0};
        if (grow < n) {
            const uint4* hr = reinterpret_cast<const uint4*>(H + (size_t)grow * 64 + cg * 16);
            v0 = hr[0]; v1 = hr[1];
        }
        uint4* dst = reinterpret_cast<uint4*>(&Hs[row * XS_STRIDE + cg * 16]);
        dst[0] = v0; dst[1] = v1;
    }
    for (int idx = tid; idx < 2048; idx += 256) {
        int c = idx & 31, k = idx >> 5;
        float v = (c < 16) ? W2a[k * 16 + c] : W2b[k * 16 + (c - 16)];
        Wt[c * XS_STRIDE + k] = f2bf(v);
    }
    __syncthreads();

    const int wid = tid >> 6, lane = tid & 63;
    const int lrow = lane & 15;
    const int lk = (lane >> 4) * 8;
    const int rq = (lane >> 4) * 4;

    short8_t a0 = *reinterpret_cast<const short8_t*>(&Hs[(wid * 16 + lrow) * XS_STRIDE + lk]);
    short8_t a1 = *reinterpret_cast<const short8_t*>(&Hs[(wid * 16 + lrow) * XS_STRIDE + 32 + lk]);

    f32x4 c0 = {0.f, 0.f, 0.f, 0.f}, c1 = {0.f, 0.f, 0.f, 0.f};
    {
        short8_t b0 = *reinterpret_cast<const short8_t*>(&Wt[lrow * XS_STRIDE + lk]);
        short8_t b1 = *reinterpret_cast<const short8_t*>(&Wt[lrow * XS_STRIDE + 32 + lk]);
        c0 = __builtin_amdgcn_mfma_f32_16x16x32_bf16(a0, b0, c0, 0, 0, 0);
        c0 = __builtin_amdgcn_mfma_f32_16x16x32_bf16(a1, b1, c0, 0, 0, 0);
    }
    {
        short8_t b0 = *reinterpret_cast<const short8_t*>(&Wt[(16 + lrow) * XS_STRIDE + lk]);
        short8_t b1 = *reinterpret_cast<const short8_t*>(&Wt[(16 + lrow) * XS_STRIDE + 32 + lk]);
        c1 = __builtin_amdgcn_mfma_f32_16x16x32_bf16(a0, b0, c1, 0, 0, 0);
        c1 = __builtin_amdgcn_mfma_f32_16x16x32_bf16(a1, b1, c1, 0, 0, 0);
    }
    #pragma unroll
    for (int r = 0; r < 4; ++r) {
        int node = rowbase + wid * 16 + rq + r;
        if (node < n) {
            float2 dv = dinv[node];
            za[(size_t)node * 16 + lrow] = f2bf(c0[r] * dv.x);
            zb[(size_t)node * 16 + lrow] = f2bf(c1[r] * dv.y);
        }
    }
}

// ---- fused dual-relation aggregation, layer 1 (bf16, F=64), h out bf16 ----
// uint2 gather lanes (4 edges/instr) + a/b relation streams interleaved for MLP.
__global__ void __launch_bounds__(256, 8)
agg64_dual_kernel(const ushort_t* __restrict__ ya, const ushort_t* __restrict__ yb,
                  const int4* __restrict__ rowse4, const int* __restrict__ col2,
                  const float2* __restrict__ dinv,
                  const float* __restrict__ ba, const float* __restrict__ bb,
                  ushort_t* __restrict__ h, int n) {
    const int lane = threadIdx.x & 63;
    const int quarter = lane >> 4;
    const int fp = lane & 15;            // feats 4fp..4fp+3
    const int gw = (blockIdx.x * blockDim.x + threadIdx.x) >> 6;
    const int nw = (gridDim.x * blockDim.x) >> 6;
    const float bi0 = ba[4 * fp] + bb[4 * fp];
    const float bi1 = ba[4 * fp + 1] + bb[4 * fp + 1];
    const float bi2 = ba[4 * fp + 2] + bb[4 * fp + 2];
    const float bi3 = ba[4 * fp + 3] + bb[4 * fp + 3];
    for (int i = gw; i < n; i += nw) {
        const int4 se = rowse4[i];
        const float2 dv = dinv[i];
        float a0 = 0.f, a1 = 0.f, a2 = 0.f, a3 = 0.f;
        float c0 = 0.f, c1 = 0.f, c2 = 0.f, c3 = 0.f;
        const int ma = min(64, se.y - se.x);
        const int mb = min(64, se.w - se.z);
        // issue both col loads up front
        int cva = (lane < ma) ? col2[se.x + lane] : 0;
        int cvb = (lane < mb) ? col2[se.z + lane] : 0;
        if (quarter == 0) {
            uint2 g = *reinterpret_cast<const uint2*>(ya + (size_t)i * 64 + 4 * fp);
            a0 = bf2f_lo(g.x); a1 = bf2f_hi(g.x); a2 = bf2f_lo(g.y); a3 = bf2f_hi(g.y);
            uint2 gb = *reinterpret_cast<const uint2*>(yb + (size_t)i * 64 + 4 * fp);
            c0 = bf2f_lo(gb.x); c1 = bf2f_hi(gb.x); c2 = bf2f_lo(gb.y); c3 = bf2f_hi(gb.y);
        }
        const int fa = ma & ~7, fb = mb & ~7;
        const int fc = fa < fb ? fa : fb;
        int j = 0;
        // interleaved full blocks: 4 independent gather loads in flight
        for (; j < fc; j += 8) {
            int ea0 = __shfl(cva, j + quarter);
            int eb0 = __shfl(cvb, j + quarter);
            int ea1 = __shfl(cva, j + 4 + quarter);
            int eb1 = __shfl(cvb, j + 4 + quarter);
            uint2 g0 = *reinterpret_cast<const uint2*>(ya + (size_t)ea0 * 64 + 4 * fp);
            uint2 G0 = *reinterpret_cast<const uint2*>(yb + (size_t)eb0 * 64 + 4 * fp);
            uint2 g1 = *reinterpret_cast<const uint2*>(ya + (size_t)ea1 * 64 + 4 * fp);
            uint2 G1 = *reinterpret_cast<const uint2*>(yb + (size_t)eb1 * 64 + 4 * fp);
            a0 += bf2f_lo(g0.x) + bf2f_lo(g1.x);
            a1 += bf2f_hi(g0.x) + bf2f_hi(g1.x);
            a2 += bf2f_lo(g0.y) + bf2f_lo(g1.y);
            a3 += bf2f_hi(g0.y) + bf2f_hi(g1.y);
            c0 += bf2f_lo(G0.x) + bf2f_lo(G1.x);
            c1 += bf2f_hi(G0.x) + bf2f_hi(G1.x);
            c2 += bf2f_lo(G0.y) + bf2f_lo(G1.y);
            c3 += bf2f_hi(G0.y) + bf2f_hi(G1.y);
        }
        // remaining a-only full blocks
        for (int jj = j; jj < fa; jj += 8) {
            int e0 = __shfl(cva, jj + quarter);
            int e1 = __shfl(cva, jj + 4 + quarter);
            uint2 g0 = *reinterpret_cast<const uint2*>(ya + (size_t)e0 * 64 + 4 * fp);
            uint2 g1 = *reinterpret_cast<const uint2*>(ya + (size_t)e1 * 64 + 4 * fp);
            a0 += bf2f_lo(g0.x) + bf2f_lo(g1.x);
            a1 += bf2f_hi(g0.x) + bf2f_hi(g1.x);
            a2 += bf2f_lo(g0.y) + bf2f_lo(g1.y);
            a3 += bf2f_hi(g0.y) + bf2f_hi(g1.y);
        }
        // remaining b-only full blocks
        for (int jj = j; jj < fb; jj += 8) {
            int e0 = __shfl(cvb, jj + quarter);
            int e1 = __shfl(cvb, jj + 4 + quarter);
            uint2 g0 = *reinterpret_cast<const uint2*>(yb + (size_t)e0 * 64 + 4 * fp);
            uint2 g1 = *reinterpret_cast<const uint2*>(yb + (size_t)e1 * 64 + 4 * fp);
            c0 += bf2f_lo(g0.x) + bf2f_lo(g1.x);
            c1 += bf2f_hi(g0.x) + bf2f_hi(g1.x);
            c2 += bf2f_lo(g0.y) + bf2f_lo(g1.y);
            c3 += bf2f_hi(g0.y) + bf2f_hi(g1.y);
        }
        // a tail (<8 edges)
        {
            int i0 = fa + quarter, i1 = fa + 4 + quarter;
            int e0 = __shfl(cva, i0 & 63);
            int e1 = __shfl(cva, i1 & 63);
            if (i0 < ma) {
                uint2 g = *reinterpret_cast<const uint2*>(ya + (size_t)e0 * 64 + 4 * fp);
                a0 += bf2f_lo(g.x); a1 += bf2f_hi(g.x);
                a2 += bf2f_lo(g.y); a3 += bf2f_hi(g.y);
            }
            if (i1 < ma) {
                uint2 g = *reinterpret_cast<const uint2*>(ya + (size_t)e1 * 64 + 4 * fp);
                a0 += bf2f_lo(g.x); a1 += bf2f_hi(g.x);
                a2 += bf2f_lo(g.y); a3 += bf2f_hi(g.y);
            }
        }
        // b tail (<8 edges)
        {
            int i0 = fb + quarter, i1 = fb + 4 + quarter;
            int e0 = __shfl(cvb, i0 & 63);
            int e1 = __shfl(cvb, i1 & 63);
            if (i0 < mb) {
                uint2 g = *reinterpret_cast<const uint2*>(yb + (size_t)e0 * 64 + 4 * fp);
                c0 += bf2f_lo(g.x); c1 += bf2f_hi(g.x);
                c2 += bf2f_lo(g.y); c3 += bf2f_hi(g.y);
            }
            if (i1 < mb) {
                uint2 g = *reinterpret_cast<const uint2*>(yb + (size_t)e1 * 64 + 4 * fp);
                c0 += bf2f_lo(g.x); c1 += bf2f_hi(g.x);
                c2 += bf2f_lo(g.y); c3 += bf2f_hi(g.y);
            }
        }
        // rare degree > 64 continuation blocks
        for (int base0 = se.x + 64; base0 < se.y; base0 += 64) {
            const int m = min(64, se.y - base0);
            int cv = (lane < m) ? col2[base0 + lane] : 0;
            int jj = 0;
            for (; jj + 8 <= m; jj += 8) {
                int e0 = __shfl(cv, jj + quarter);
                int e1 = __shfl(cv, jj + 4 + quarter);
                uint2 g0 = *reinterpret_cast<const uint2*>(ya + (size_t)e0 * 64 + 4 * fp);
                uint2 g1 = *reinterpret_cast<const uint2*>(ya + (size_t)e1 * 64 + 4 * fp);
                a0 += bf2f_lo(g0.x) + bf2f_lo(g1.x);
                a1 += bf2f_hi(g0.x) + bf2f_hi(g1.x);
                a2 += bf2f_lo(g0.y) + bf2f_lo(g1.y);
                a3 += bf2f_hi(g0.y) + bf2f_hi(g1.y);
            }
            int i0 = jj + quarter, i1 = jj + 4 + quarter;
            int e0 = __shfl(cv, i0 & 63);
            int e1 = __shfl(cv, i1 & 63);
            if (i0 < m) {
                uint2 g = *reinterpret_cast<const uint2*>(ya + (size_t)e0 * 64 + 4 * fp);
                a0 += bf2f_lo(g.x); a1 += bf2f_hi(g.x);
                a2 += bf2f_lo(g.y); a3 += bf2f_hi(g.y);
            }
            if (i1 < m) {
                uint2 g = *reinterpret_cast<const uint2*>(ya + (size_t)e1 * 64 + 4 * fp);
                a0 += bf2f_lo(g.x); a1 += bf2f_hi(g.x);
                a2 += bf2f_lo(g.y); a3 += bf2f_hi(g.y);
            }
        }
        for (int base0 = se.z + 64; base0 < se.w; base0 += 64) {
            const int m = min(64, se.w - base0);
            int cv = (lane < m) ? col2[base0 + lane] : 0;
            int jj = 0;
            for (; jj + 8 <= m; jj += 8) {
                int e0 = __shfl(cv, jj + quarter);
                int e1 = __shfl(cv, jj + 4 + quarter);
                uint2 g0 = *reinterpret_cast<const uint2*>(yb + (size_t)e0 * 64 + 4 * fp);
                uint2 g1 = *reinterpret_cast<const uint2*>(yb + (size_t)e1 * 64 + 4 * fp);
                c0 += bf2f_lo(g0.x) + bf2f_lo(g1.x);
                c1 += bf2f_hi(g0.x) + bf2f_hi(g1.x);
                c2 += bf2f_lo(g0.y) + bf2f_lo(g1.y);
                c3 += bf2f_hi(g0.y) + bf2f_hi(g1.y);
            }
            int i0 = jj + quarter, i1 = jj + 4 + quarter;
            int e0 = __shfl(cv, i0 & 63);
            int e1 = __shfl(cv, i1 & 63);
            if (i0 < m) {
                uint2 g = *reinterpret_cast<const uint2*>(yb + (size_t)e0 * 64 + 4 * fp);
                c0 += bf2f_lo(g.x); c1 += bf2f_hi(g.x);
                c2 += bf2f_lo(g.y); c3 += bf2f_hi(g.y);
            }
            if (i1 < m) {
                uint2 g = *reinterpret_cast<const uint2*>(yb + (size_t)e1 * 64 + 4 * fp);
                c0 += bf2f_lo(g.x); c1 += bf2f_hi(g.x);
                c2 += bf2f_lo(g.y); c3 += bf2f_hi(g.y);
            }
        }
        // combine with dinv per-lane, then reduce over quarters
        float v0 = a0 * dv.x + c0 * dv.y;
        float v1 = a1 * dv.x + c1 * dv.y;
        float v2 = a2 * dv.x + c2 * dv.y;
        float v3 = a3 * dv.x + c3 * dv.y;
        v0 += __shfl_xor(v0, 16); v1 += __shfl_xor(v1, 16);
        v2 += __shfl_xor(v2, 16); v3 += __shfl_xor(v3, 16);
        v0 += __shfl_xor(v0, 32); v1 += __shfl_xor(v1, 32);
        v2 += __shfl_xor(v2, 32); v3 += __shfl_xor(v3, 32);
        if (quarter == 0) {
            float r0 = fmaxf(0.5f * (v0 + bi0), 0.0f);
            float r1 = fmaxf(0.5f * (v1 + bi1), 0.0f);
            float r2 = fmaxf(0.5f * (v2 + bi2), 0.0f);
            float r3 = fmaxf(0.5f * (v3 + bi3), 0.0f);
            uint2 p;
            p.x = (uint_t)f2bf(r0) | ((uint_t)f2bf(r1) << 16);
            p.y = (uint_t)f2bf(r2) | ((uint_t)f2bf(r3) << 16);
            *reinterpret_cast<uint2*>(h + (size_t)i * 64 + 4 * fp) = p;
        }
    }
}

// ---- fused dual-relation aggregation, layer 2 (bf16, F=16) ----
// lane = (8 edge-slots, 8 feat-pairs); one instruction = 8 edges; a/b interleaved.
__global__ void __launch_bounds__(256, 8)
agg16_dual_kernel(const ushort_t* __restrict__ za, const ushort_t* __restrict__ zb,
                  const int4* __restrict__ rowse4, const int* __restrict__ col2,
                  const float2* __restrict__ dinv,
                  const float* __restrict__ ba, const float* __restrict__ bb,
                  float* __restrict__ outp, int n) {
    const int lane = threadIdx.x & 63;
    const int fp   = lane & 7;        // feats 2fp, 2fp+1
    const int sub  = lane >> 3;       // 0..7 edge slots
    const int gw   = (blockIdx.x * blockDim.x + threadIdx.x) >> 6;
    const int nw   = (gridDim.x * blockDim.x) >> 6;
    const float bx = ba[2 * fp] + bb[2 * fp];
    const float by = ba[2 * fp + 1] + bb[2 * fp + 1];
    for (int i = gw; i < n; i += nw) {
        const int4 se = rowse4[i];
        const float2 dv = dinv[i];
        int ea = se.x + sub, eb = se.z + sub;
        const int e1a = se.y, e1b = se.w;
        float ax = 0.f, ay = 0.f, bx2 = 0.f, by2 = 0.f;
        if (sub == 0) {
            uint_t ga = *reinterpret_cast<const uint_t*>(za + (size_t)i * 16 + 2 * fp);
            uint_t gb = *reinterpret_cast<const uint_t*>(zb + (size_t)i * 16 + 2 * fp);
            ax = bf2f_lo(ga); ay = bf2f_hi(ga);
            bx2 = bf2f_lo(gb); by2 = bf2f_hi(gb);
        }
        for (; ea + 8 < e1a && eb + 8 < e1b; ea += 16, eb += 16) {
            int c0 = col2[ea], c1 = col2[ea + 8];
            int d0 = col2[eb], d1 = col2[eb + 8];
            uint_t g0 = *reinterpret_cast<const uint_t*>(za + (size_t)c0 * 16 + 2 * fp);
            uint_t g1 = *reinterpret_cast<const uint_t*>(za + (size_t)c1 * 16 + 2 * fp);
            uint_t g2 = *reinterpret_cast<const uint_t*>(zb + (size_t)d0 * 16 + 2 * fp);
            uint_t g3 = *reinterpret_cast<const uint_t*>(zb + (size_t)d1 * 16 + 2 * fp);
            ax += bf2f_lo(g0) + bf2f_lo(g1);  ay += bf2f_hi(g0) + bf2f_hi(g1);
            bx2 += bf2f_lo(g2) + bf2f_lo(g3); by2 += bf2f_hi(g2) + bf2f_hi(g3);
        }
        for (; ea < e1a; ea += 8) {
            uint_t g = *reinterpret_cast<const uint_t*>(za + (size_t)col2[ea] * 16 + 2 * fp);
            ax += bf2f_lo(g); ay += bf2f_hi(g);
        }
        for (; eb < e1b; eb += 8) {
            uint_t g = *reinterpret_cast<const uint_t*>(zb + (size_t)col2[eb] * 16 + 2 * fp);
            bx2 += bf2f_lo(g); by2 += bf2f_hi(g);
        }
        float vx = ax * dv.x + bx2 * dv.y;
        float vy = ay * dv.x + by2 * dv.y;
        vx += __shfl_xor(vx, 8);  vy += __shfl_xor(vy, 8);
        vx += __shfl_xor(vx, 16); vy += __shfl_xor(vy, 16);
        vx += __shfl_xor(vx, 32); vy += __shfl_xor(vy, 32);
        if (sub == 0) {
            float2 o = make_float2(0.5f * (vx + bx), 0.5f * (vy + by));
            *reinterpret_cast<float2*>(outp + (size_t)i * 16 + 2 * fp) = o;
        }
    }
}

extern "C" void kernel_launch(void* const* d_in, const int* in_sizes, int n_in,
                              void* d_out, int out_size, void* d_ws, size_t ws_size,
                              hipStream_t stream) {
    const float* x   = (const float*)d_in[0];
    const int*   eia = (const int*)d_in[1];
    const int*   eib = (const int*)d_in[2];
    const float* W1a = (const float*)d_in[3];
    const float* b1a = (const float*)d_in[4];
    const float* W1b = (const float*)d_in[5];
    const float* b1b = (const float*)d_in[6];
    const float* W2a = (const float*)d_in[7];
    const float* b2a = (const float*)d_in[8];
    const float* W2b = (const float*)d_in[9];
    const float* b2b = (const float*)d_in[10];
    float* out = (float*)d_out;

    const int n  = in_sizes[0] / 64;
    const int Ea = in_sizes[1] / 2;
    const int Eb = in_sizes[2] / 2;
    const int Et = Ea + Eb;
    const int n2 = 2 * n;

    int shift = 10;
    while ((((long long)n + (1LL << shift) - 1) >> shift) > 128) ++shift;
    const int nbuk = (int)(((long long)n + (1LL << shift) - 1) >> shift);
    const int nbuk2 = 2 * nbuk;
    const int Emaxrel = Ea > Eb ? Ea : Eb;
    int CAP = ((Emaxrel / (nbuk > 0 ? nbuk : 1)) * 3) / 2 + 2048;
    CAP = (CAP + 63) & ~63;

    char* wsp = (char*)d_ws;
    size_t off = 0;
    auto carve = [&](size_t elems) { void* p = wsp + off; off += ((elems + 3) & ~(size_t)3) * 4; return p; };
    float* dinv     = (float*)carve(n2);               // [n][2] interleaved
    int*   rowse    = (int*)carve((size_t)n * 4);      // [n][4] interleaved
    int*   bcursor2 = (int*)carve(MAXBUK);
    int*   col2     = (int*)carve((size_t)nbuk2 * CAP);
    ushort_t* ya    = (ushort_t*)carve((size_t)32 * n);   // 64n bf16
    ushort_t* yb    = (ushort_t*)carve((size_t)32 * n);
    ushort_t* za    = (ushort_t*)carve((size_t)8 * n);    // 16n bf16
    ushort_t* zb    = (ushort_t*)carve((size_t)8 * n);
    size_t pair_words = (size_t)nbuk2 * CAP;
    size_t big_words = pair_words > (size_t)32 * n ? pair_words : (size_t)32 * n;
    void*  big      = carve(big_words);
    uint_t* pairs   = (uint_t*)big;
    ushort_t* H     = (ushort_t*)big;

    const int T = 256;
    auto cdiv = [](long long a, long long b) { return (unsigned)((a + b - 1) / b); };

    // ---- combined CSR build (no pre-count pass) ----
    init_caps_kernel<<<1, 256, 0, stream>>>(bcursor2, nbuk2, CAP);
    bfill2_kernel<<<cdiv(Et, BF_CHUNK), T, 0, stream>>>(eia, eib, bcursor2, pairs,
                                                        Ea, Eb, Et, shift, nbuk, n);
    if (shift == 10)
        bucket_csr_kernel<1024><<<nbuk2, 1024, 0, stream>>>(pairs, bcursor2, rowse, dinv,
                                                            col2, nbuk, shift, n, CAP);
    else if (shift == 11)
        bucket_csr_kernel<2048><<<nbuk2, 1024, 0, stream>>>(pairs, bcursor2, rowse, dinv,
                                                            col2, nbuk, shift, n, CAP);
    else
        bucket_csr_kernel<4096><<<nbuk2, 1024, 0, stream>>>(pairs, bcursor2, rowse, dinv,
                                                            col2, nbuk, shift, n, CAP);

    const unsigned AGG_GRID = 2048;

    // ---- layer 1 ----
    gemm2_mfma_bf16_kernel<<<cdiv(n, 64), T, 0, stream>>>(x, W1a, W1b, (const float2*)dinv, ya, yb, n);
    agg64_dual_kernel<<<AGG_GRID, T, 0, stream>>>(ya, yb, (const int4*)rowse, col2,
                                                  (const float2*)dinv, b1a, b1b, H, n);

    // ---- layer 2 ----
    gemm2_mfma_h_kernel<<<cdiv(n, 64), T, 0, stream>>>(H, W2a, W2b, (const float2*)dinv, za, zb, n);
    agg16_dual_kernel<<<AGG_GRID, T, 0, stream>>>(za, zb, (const int4*)rowse, col2,
                                                  (const float2*)dinv, b2a, b2b, out, n);
}